// Round 1
// baseline (1820.629 us; speedup 1.0000x reference)
//
#include <hip/hip_runtime.h>
#include <math.h>

#define F_IN 500
#define F_HID 128
#define F_OUT 47

// ---------------- degree / norm ----------------
__global__ void k_deg_init(int* __restrict__ deg, int n) {
    int i = blockIdx.x * 256 + threadIdx.x;
    if (i < n) deg[i] = 1;  // self-loop
}

__global__ void k_deg_count(const int* __restrict__ ei, int* __restrict__ deg, int E) {
    int e = blockIdx.x * 256 + threadIdx.x;
    if (e < E) atomicAdd(&deg[ei[E + e]], 1);  // dst = ei[1][e]
}

__global__ void k_dinv(float* __restrict__ dinv_io, int n) {
    int i = blockIdx.x * 256 + threadIdx.x;
    if (i < n) {
        int d = ((const int*)dinv_io)[i];
        dinv_io[i] = rsqrtf((float)d);
    }
}

// ---------------- GEMM1: hs = (x @ W1) * dinv, acc = hs ----------------
#define G1_NODES 32
__global__ __launch_bounds__(256) void k_gemm1(const float* __restrict__ x,
                                               const float* __restrict__ W1,
                                               const float* __restrict__ dinv,
                                               float* __restrict__ hs,
                                               float* __restrict__ acc, int n) {
    __shared__ float xs[G1_NODES * F_IN];
    int base = blockIdx.x * G1_NODES;
    for (int idx = threadIdx.x; idx < G1_NODES * F_IN; idx += 256) {
        int nd = idx / F_IN, k = idx - nd * F_IN;
        int node = base + nd;
        xs[idx] = (node < n) ? x[(long)node * F_IN + k] : 0.f;
    }
    __syncthreads();
    int colg = (threadIdx.x & 31) * 4;   // 0..124
    int ng   = (threadIdx.x >> 5) * 4;   // 0..28
    float a[4][4] = {};
    for (int k = 0; k < F_IN; ++k) {
        float4 w = *(const float4*)&W1[k * F_HID + colg];
#pragma unroll
        for (int i = 0; i < 4; ++i) {
            float xv = xs[(ng + i) * F_IN + k];
            a[i][0] += xv * w.x; a[i][1] += xv * w.y;
            a[i][2] += xv * w.z; a[i][3] += xv * w.w;
        }
    }
#pragma unroll
    for (int i = 0; i < 4; ++i) {
        int node = base + ng + i;
        if (node < n) {
            float dv = dinv[node];
            float4 o = make_float4(a[i][0] * dv, a[i][1] * dv, a[i][2] * dv, a[i][3] * dv);
            *(float4*)&hs[(long)node * F_HID + colg]  = o;
            *(float4*)&acc[(long)node * F_HID + colg] = o;
        }
    }
}

// ---------------- edge scatter layer 1: acc[dst] += hs[src] ----------------
__global__ void k_scatter1(const int* __restrict__ ei, const float* __restrict__ hs,
                           float* __restrict__ acc, int E) {
    int tid = blockIdx.x * 256 + threadIdx.x;
    int e = tid >> 5;
    if (e >= E) return;
    int q = (tid & 31) * 4;
    int s = ei[e], d = ei[E + e];
    float4 v = *(const float4*)&hs[(long)s * F_HID + q];
    atomicAdd(&acc[(long)d * F_HID + q + 0], v.x);
    atomicAdd(&acc[(long)d * F_HID + q + 1], v.y);
    atomicAdd(&acc[(long)d * F_HID + q + 2], v.z);
    atomicAdd(&acc[(long)d * F_HID + q + 3], v.w);
}

// ---------------- layer1 epilogue + GEMM2: hs2 = relu(dinv*acc+b1) @ W2 * dinv ----------------
__global__ __launch_bounds__(256) void k_layer2(const float* __restrict__ acc,
                                                const float* __restrict__ b1,
                                                const float* __restrict__ W2,
                                                const float* __restrict__ dinv,
                                                float* __restrict__ hs2,
                                                float* __restrict__ out_acc2, int n) {
    __shared__ float w2s[F_HID * F_OUT];
    __shared__ float rs[4][F_HID];
    for (int i = threadIdx.x; i < F_HID * F_OUT; i += 256) w2s[i] = W2[i];
    int w = threadIdx.x >> 6, lane = threadIdx.x & 63;
    int node = blockIdx.x * 4 + w;
    if (node < n) {
        float dv = dinv[node];
        for (int k = lane; k < F_HID; k += 64)
            rs[w][k] = fmaxf(dv * acc[(long)node * F_HID + k] + b1[k], 0.f);
    }
    __syncthreads();
    if (node < n && lane < F_OUT) {
        float s = 0.f;
#pragma unroll 8
        for (int k = 0; k < F_HID; ++k) s += rs[w][k] * w2s[k * F_OUT + lane];
        float v = s * dinv[node];
        hs2[(long)node * F_OUT + lane]      = v;
        out_acc2[(long)node * F_OUT + lane] = v;
    }
}

// ---------------- edge scatter layer 2 ----------------
__global__ void k_scatter2(const int* __restrict__ ei, const float* __restrict__ hs2,
                           float* __restrict__ out, int E) {
    int w = threadIdx.x >> 6, lane = threadIdx.x & 63;
    int e = blockIdx.x * 4 + w;
    if (e >= E || lane >= F_OUT) return;
    int s = ei[e], d = ei[E + e];
    atomicAdd(&out[(long)d * F_OUT + lane], hs2[(long)s * F_OUT + lane]);
}

// ---------------- out = log_softmax(dinv*acc2 + b2) ----------------
__global__ void k_logsoftmax(float* __restrict__ out, const float* __restrict__ dinv,
                             const float* __restrict__ b2, int n) {
    int w = threadIdx.x >> 6, lane = threadIdx.x & 63;
    int node = blockIdx.x * 4 + w;
    if (node >= n) return;
    float dv = dinv[node];
    float z = -INFINITY;
    if (lane < F_OUT) z = dv * out[(long)node * F_OUT + lane] + b2[lane];
    float m = z;
#pragma unroll
    for (int o = 32; o; o >>= 1) m = fmaxf(m, __shfl_xor(m, o));
    float ev = (lane < F_OUT) ? __expf(z - m) : 0.f;
    float sum = ev;
#pragma unroll
    for (int o = 32; o; o >>= 1) sum += __shfl_xor(sum, o);
    float ls = logf(sum);
    if (lane < F_OUT) out[(long)node * F_OUT + lane] = z - m - ls;
}

extern "C" void kernel_launch(void* const* d_in, const int* in_sizes, int n_in,
                              void* d_out, int out_size, void* d_ws, size_t ws_size,
                              hipStream_t stream) {
    const float* x  = (const float*)d_in[0];
    const float* W1 = (const float*)d_in[1];
    const float* b1 = (const float*)d_in[2];
    const float* W2 = (const float*)d_in[3];
    const float* b2 = (const float*)d_in[4];
    const int*   ei = (const int*)d_in[5];

    int n = in_sizes[0] / F_IN;      // 50000
    int E = in_sizes[5] / 2;         // 800000
    float* out = (float*)d_out;

    // workspace layout (256B aligned)
    char* ws = (char*)d_ws;
    float* dinv = (float*)ws;                               // 50000*4   (also deg as int)
    float* hs   = (float*)(ws + 200704);                    // 50000*128*4
    float* acc  = (float*)(ws + 200704 + 25600000);         // 50000*128*4
    float* hs2  = (float*)(ws + 200704 + 2 * 25600000);     // 50000*47*4

    int nb = (n + 255) / 256;
    k_deg_init<<<nb, 256, 0, stream>>>((int*)dinv, n);
    k_deg_count<<<(E + 255) / 256, 256, 0, stream>>>(ei, (int*)dinv, E);
    k_dinv<<<nb, 256, 0, stream>>>(dinv, n);

    k_gemm1<<<(n + G1_NODES - 1) / G1_NODES, 256, 0, stream>>>(x, W1, dinv, hs, acc, n);

    k_scatter1<<<(E * 32 + 255) / 256, 256, 0, stream>>>(ei, hs, acc, E);

    k_layer2<<<(n + 3) / 4, 256, 0, stream>>>(acc, b1, W2, dinv, hs2, out, n);

    k_scatter2<<<(E + 3) / 4, 256, 0, stream>>>(ei, hs2, out, E);

    k_logsoftmax<<<(n + 3) / 4, 256, 0, stream>>>(out, dinv, b2, n);
}

// Round 2
// 593.549 us; speedup vs baseline: 3.0674x; 3.0674x over previous
//
#include <hip/hip_runtime.h>
#include <math.h>

#define F_IN 500
#define F_HID 128
#define F_OUT 47

// ---------------- degree / norm / CSR build ----------------
__global__ void k_zero(int* __restrict__ p, int n) {
    int i = blockIdx.x * 256 + threadIdx.x;
    if (i < n) p[i] = 0;
}

__global__ void k_deg_count(const int* __restrict__ ei, int* __restrict__ ecnt, int E) {
    int e = blockIdx.x * 256 + threadIdx.x;
    if (e < E) atomicAdd(&ecnt[ei[E + e]], 1);  // dst = ei[1][e]
}

__global__ void k_dinv(const int* __restrict__ ecnt, float* __restrict__ dinv, int n) {
    int i = blockIdx.x * 256 + threadIdx.x;
    if (i < n) dinv[i] = rsqrtf((float)(ecnt[i] + 1));  // +1 self-loop
}

// single-block exclusive scan of ecnt -> rowptr (and cur copy)
__global__ __launch_bounds__(1024) void k_scan(const int* __restrict__ ecnt,
                                               int* __restrict__ rowptr,
                                               int* __restrict__ cur, int n) {
    __shared__ int partial[1024];
    int t = threadIdx.x;
    int chunk = (n + 1023) / 1024;
    int lo = t * chunk, hi = min(lo + chunk, n);
    int s = 0;
    for (int i = lo; i < hi; ++i) s += ecnt[i];
    partial[t] = s;
    __syncthreads();
    for (int off = 1; off < 1024; off <<= 1) {
        int v = (t >= off) ? partial[t - off] : 0;
        __syncthreads();
        partial[t] += v;
        __syncthreads();
    }
    int base = (t == 0) ? 0 : partial[t - 1];
    for (int i = lo; i < hi; ++i) {
        rowptr[i] = base;
        cur[i] = base;
        base += ecnt[i];
    }
    if (t == 1023) rowptr[n] = partial[1023];
}

__global__ void k_fill(const int* __restrict__ ei, int* __restrict__ cur,
                       int* __restrict__ csr, int E) {
    int e = blockIdx.x * 256 + threadIdx.x;
    if (e < E) {
        int d = ei[E + e];
        int pos = atomicAdd(&cur[d], 1);
        csr[pos] = ei[e];  // src
    }
}

// ---------------- GEMM1: hs = (x @ W1) * dinv ----------------
#define G1_NODES 32
__global__ __launch_bounds__(256) void k_gemm1(const float* __restrict__ x,
                                               const float* __restrict__ W1,
                                               const float* __restrict__ dinv,
                                               float* __restrict__ hs, int n) {
    __shared__ float xs[G1_NODES * F_IN];
    int base = blockIdx.x * G1_NODES;
    for (int idx = threadIdx.x; idx < G1_NODES * F_IN; idx += 256) {
        int nd = idx / F_IN, k = idx - nd * F_IN;
        int node = base + nd;
        xs[idx] = (node < n) ? x[(long)node * F_IN + k] : 0.f;
    }
    __syncthreads();
    int colg = (threadIdx.x & 31) * 4;   // 0..124
    int ng   = (threadIdx.x >> 5) * 4;   // 0..28
    float a[4][4] = {};
    for (int k = 0; k < F_IN; ++k) {
        float4 w = *(const float4*)&W1[k * F_HID + colg];
#pragma unroll
        for (int i = 0; i < 4; ++i) {
            float xv = xs[(ng + i) * F_IN + k];
            a[i][0] += xv * w.x; a[i][1] += xv * w.y;
            a[i][2] += xv * w.z; a[i][3] += xv * w.w;
        }
    }
#pragma unroll
    for (int i = 0; i < 4; ++i) {
        int node = base + ng + i;
        if (node < n) {
            float dv = dinv[node];
            *(float4*)&hs[(long)node * F_HID + colg] =
                make_float4(a[i][0] * dv, a[i][1] * dv, a[i][2] * dv, a[i][3] * dv);
        }
    }
}

// ---------------- gather layer 1 + epilogue: h1 = relu(dinv * (hs[self]+sum hs[src]) + b1) ----------------
__global__ __launch_bounds__(256) void k_gather1(const float* __restrict__ hs,
                                                 const int* __restrict__ rowptr,
                                                 const int* __restrict__ csr,
                                                 const float* __restrict__ dinv,
                                                 const float* __restrict__ b1,
                                                 float* __restrict__ h1, int n) {
    int tid = blockIdx.x * 256 + threadIdx.x;
    int node = tid >> 5;
    if (node >= n) return;
    int q = (tid & 31) * 4;
    float4 v = *(const float4*)&hs[(long)node * F_HID + q];  // self-loop
    int lo = rowptr[node], hi = rowptr[node + 1];
    for (int e = lo; e < hi; ++e) {
        int s = csr[e];
        float4 u = *(const float4*)&hs[(long)s * F_HID + q];
        v.x += u.x; v.y += u.y; v.z += u.z; v.w += u.w;
    }
    float dv = dinv[node];
    float4 bb = *(const float4*)&b1[q];
    *(float4*)&h1[(long)node * F_HID + q] =
        make_float4(fmaxf(dv * v.x + bb.x, 0.f), fmaxf(dv * v.y + bb.y, 0.f),
                    fmaxf(dv * v.z + bb.z, 0.f), fmaxf(dv * v.w + bb.w, 0.f));
}

// ---------------- GEMM2: hs2 = (h1 @ W2) * dinv ----------------
__global__ __launch_bounds__(256) void k_gemm2(const float* __restrict__ h1,
                                               const float* __restrict__ W2,
                                               const float* __restrict__ dinv,
                                               float* __restrict__ hs2, int n) {
    __shared__ float w2s[F_HID * F_OUT];
    __shared__ float rs[4][F_HID];
    for (int i = threadIdx.x; i < F_HID * F_OUT; i += 256) w2s[i] = W2[i];
    int w = threadIdx.x >> 6, lane = threadIdx.x & 63;
    int node = blockIdx.x * 4 + w;
    if (node < n) {
        for (int k = lane; k < F_HID; k += 64)
            rs[w][k] = h1[(long)node * F_HID + k];
    }
    __syncthreads();
    if (node < n && lane < F_OUT) {
        float s = 0.f;
#pragma unroll 8
        for (int k = 0; k < F_HID; ++k) s += rs[w][k] * w2s[k * F_OUT + lane];
        hs2[(long)node * F_OUT + lane] = s * dinv[node];
    }
}

// ---------------- gather layer 2 + bias + log_softmax ----------------
__global__ __launch_bounds__(256) void k_out(const float* __restrict__ hs2,
                                             const int* __restrict__ rowptr,
                                             const int* __restrict__ csr,
                                             const float* __restrict__ dinv,
                                             const float* __restrict__ b2,
                                             float* __restrict__ out, int n) {
    int w = threadIdx.x >> 6, lane = threadIdx.x & 63;
    int node = blockIdx.x * 4 + w;
    if (node >= n) return;
    float v = (lane < F_OUT) ? hs2[(long)node * F_OUT + lane] : 0.f;  // self-loop
    int lo = rowptr[node], hi = rowptr[node + 1];
    for (int e = lo; e < hi; ++e) {
        int s = csr[e];
        if (lane < F_OUT) v += hs2[(long)s * F_OUT + lane];
    }
    float z = (lane < F_OUT) ? v * dinv[node] + b2[lane] : -INFINITY;
    float m = z;
#pragma unroll
    for (int o = 32; o; o >>= 1) m = fmaxf(m, __shfl_xor(m, o));
    float ev = (lane < F_OUT) ? __expf(z - m) : 0.f;
    float sum = ev;
#pragma unroll
    for (int o = 32; o; o >>= 1) sum += __shfl_xor(sum, o);
    float ls = logf(sum);
    if (lane < F_OUT) out[(long)node * F_OUT + lane] = z - m - ls;
}

extern "C" void kernel_launch(void* const* d_in, const int* in_sizes, int n_in,
                              void* d_out, int out_size, void* d_ws, size_t ws_size,
                              hipStream_t stream) {
    const float* x  = (const float*)d_in[0];
    const float* W1 = (const float*)d_in[1];
    const float* b1 = (const float*)d_in[2];
    const float* W2 = (const float*)d_in[3];
    const float* b2 = (const float*)d_in[4];
    const int*   ei = (const int*)d_in[5];

    int n = in_sizes[0] / F_IN;      // 50000
    int E = in_sizes[5] / 2;         // 800000
    float* out = (float*)d_out;

    // workspace layout (256B aligned)
    char* ws = (char*)d_ws;
    float* dinv   = (float*)(ws + 0);          // 200 KB
    int*   ecnt   = (int*)  (ws + 200704);
    int*   rowptr = (int*)  (ws + 401408);     // n+1 ints
    int*   cur    = (int*)  (ws + 602112);
    int*   csr    = (int*)  (ws + 802816);     // E ints = 3.2 MB
    float* hs     = (float*)(ws + 4003840);    // 25.6 MB
    float* h1     = (float*)(ws + 29603840);   // 25.6 MB
    float* hs2    = hs;                         // alias: hs dead after k_gather1

    int nb = (n + 255) / 256;
    int eb = (E + 255) / 256;
    k_zero<<<nb, 256, 0, stream>>>(ecnt, n);
    k_deg_count<<<eb, 256, 0, stream>>>(ei, ecnt, E);
    k_dinv<<<nb, 256, 0, stream>>>(ecnt, dinv, n);
    k_scan<<<1, 1024, 0, stream>>>(ecnt, rowptr, cur, n);
    k_fill<<<eb, 256, 0, stream>>>(ei, cur, csr, E);

    k_gemm1<<<(n + G1_NODES - 1) / G1_NODES, 256, 0, stream>>>(x, W1, dinv, hs, n);
    k_gather1<<<(n * 32 + 255) / 256, 256, 0, stream>>>(hs, rowptr, csr, dinv, b1, h1, n);
    k_gemm2<<<(n + 3) / 4, 256, 0, stream>>>(h1, W2, dinv, hs2, n);
    k_out<<<(n + 3) / 4, 256, 0, stream>>>(hs2, rowptr, csr, dinv, b2, out, n);
}

// Round 3
// 438.553 us; speedup vs baseline: 4.1514x; 1.3534x over previous
//
#include <hip/hip_runtime.h>
#include <math.h>

#define F_IN 500
#define F_HID 128
#define F_OUT 47

typedef __attribute__((ext_vector_type(8))) short short8;
typedef __attribute__((ext_vector_type(4))) float f32x4;

__device__ inline unsigned pack_bf16x2(float a, float b) {
    unsigned ua = __float_as_uint(a), ub = __float_as_uint(b);
    ua = (ua + 0x7FFFu + ((ua >> 16) & 1u)) >> 16;
    ub = (ub + 0x7FFFu + ((ub >> 16) & 1u)) >> 16;
    return ua | (ub << 16);
}

// ---------------- degree / norm / CSR build ----------------
__global__ void k_zero(int* __restrict__ p, int n) {
    int i = blockIdx.x * 256 + threadIdx.x;
    if (i < n) p[i] = 0;
}

__global__ void k_deg_count(const int* __restrict__ ei, int* __restrict__ ecnt, int E) {
    int e = blockIdx.x * 256 + threadIdx.x;
    if (e < E) atomicAdd(&ecnt[ei[E + e]], 1);  // dst = ei[1][e]
}

__global__ void k_dinv(const int* __restrict__ ecnt, float* __restrict__ dinv, int n) {
    int i = blockIdx.x * 256 + threadIdx.x;
    if (i < n) dinv[i] = rsqrtf((float)(ecnt[i] + 1));  // +1 self-loop
}

// single-block exclusive scan of ecnt -> rowptr (and cur copy)
__global__ __launch_bounds__(1024) void k_scan(const int* __restrict__ ecnt,
                                               int* __restrict__ rowptr,
                                               int* __restrict__ cur, int n) {
    __shared__ int partial[1024];
    int t = threadIdx.x;
    int chunk = (n + 1023) / 1024;
    int lo = t * chunk, hi = min(lo + chunk, n);
    int s = 0;
    for (int i = lo; i < hi; ++i) s += ecnt[i];
    partial[t] = s;
    __syncthreads();
    for (int off = 1; off < 1024; off <<= 1) {
        int v = (t >= off) ? partial[t - off] : 0;
        __syncthreads();
        partial[t] += v;
        __syncthreads();
    }
    int base = (t == 0) ? 0 : partial[t - 1];
    for (int i = lo; i < hi; ++i) {
        rowptr[i] = base;
        cur[i] = base;
        base += ecnt[i];
    }
    if (t == 1023) rowptr[n] = partial[1023];
}

__global__ void k_fill(const int* __restrict__ ei, int* __restrict__ cur,
                       int* __restrict__ csr, int E) {
    int e = blockIdx.x * 256 + threadIdx.x;
    if (e < E) {
        int d = ei[E + e];
        int pos = atomicAdd(&cur[d], 1);
        csr[pos] = ei[e];  // src
    }
}

// ---------------- W1 -> bf16, transposed [128 cols][512 k] (k padded w/ zeros) ----------------
__global__ void k_w1cvt(const float* __restrict__ W1, unsigned short* __restrict__ Btg) {
    int id = blockIdx.x * 256 + threadIdx.x;  // 65536 total
    int kk = id >> 7, c = id & 127;
    float v = (kk < F_IN) ? W1[kk * F_HID + c] : 0.f;
    unsigned u = __float_as_uint(v);
    u = (u + 0x7FFFu + ((u >> 16) & 1u)) >> 16;
    Btg[c * 512 + kk] = (unsigned short)u;
}

// ---------------- GEMM1 (bf16 MFMA): hs = (x @ W1) * dinv ----------------
// BM=64 rows/block, BK=64, 256 thr = 4 waves (2x2), wave tile 32x64.
#define BM 64
#define BK 64
__global__ __launch_bounds__(256) void k_gemm1_mfma(const float* __restrict__ x,
                                                    const unsigned short* __restrict__ Btg,
                                                    const float* __restrict__ dinv,
                                                    float* __restrict__ hs, int n) {
    __shared__ unsigned short As[BM * BK];    // XOR-swizzled
    __shared__ unsigned short Bs[F_HID * BK]; // XOR-swizzled (B stored col-major: [col][k])
    int t = threadIdx.x;
    int row0 = blockIdx.x * BM;
    int w = t >> 6, l = t & 63;
    int wm = w >> 1, wn = w & 1;  // wave rows: wm*32.., wave cols: wn*64..

    f32x4 acc[2][4] = {};

    for (int c = 0; c < 8; ++c) {
        int k0 = c * BK;
        // ---- stage A: 64x64 fp32 -> bf16 LDS (2 units of 8 elems per thread)
#pragma unroll
        for (int uu = 0; uu < 2; ++uu) {
            int u = t + uu * 256;            // 0..511
            int r = u >> 3, cg = u & 7;
            int grow = row0 + r;
            int kbase = k0 + cg * 8;
            float4 f0 = make_float4(0.f, 0.f, 0.f, 0.f);
            float4 f1 = make_float4(0.f, 0.f, 0.f, 0.f);
            if (grow < n) {
                const float* p = x + (long)grow * F_IN + kbase;
                if (kbase + 4 <= F_IN) f0 = *(const float4*)p;
                if (kbase + 8 <= F_IN) f1 = *(const float4*)(p + 4);
            }
            uint4 pk;
            pk.x = pack_bf16x2(f0.x, f0.y);
            pk.y = pack_bf16x2(f0.z, f0.w);
            pk.z = pack_bf16x2(f1.x, f1.y);
            pk.w = pack_bf16x2(f1.z, f1.w);
            int byte = r * 128 + ((cg * 16) ^ ((r & 7) << 4));
            *(uint4*)((char*)As + byte) = pk;
        }
        // ---- stage B: 128 cols x 64 k bf16 (4 units of 8 elems per thread)
#pragma unroll
        for (int uu = 0; uu < 4; ++uu) {
            int u = t + uu * 256;            // 0..1023
            int r = u >> 3, cg = u & 7;      // r = col index 0..127
            uint4 v = *(const uint4*)(Btg + r * 512 + k0 + cg * 8);
            int byte = r * 128 + ((cg * 16) ^ ((r & 7) << 4));
            *(uint4*)((char*)Bs + byte) = v;
        }
        __syncthreads();

        // ---- fragments + MFMA
        int lr = l & 15;
        int lkb = (l >> 4) * 16;  // byte offset of this lane's 8-elem k group
        short8 af[2][2], bf[4][2];
#pragma unroll
        for (int mi = 0; mi < 2; ++mi)
#pragma unroll
            for (int ks = 0; ks < 2; ++ks) {
                int r = wm * 32 + mi * 16 + lr;
                int byte = r * 128 + (((ks * 64) + lkb) ^ ((r & 7) << 4));
                af[mi][ks] = *(short8*)((char*)As + byte);
            }
#pragma unroll
        for (int ni = 0; ni < 4; ++ni)
#pragma unroll
            for (int ks = 0; ks < 2; ++ks) {
                int r = wn * 64 + ni * 16 + lr;
                int byte = r * 128 + (((ks * 64) + lkb) ^ ((r & 7) << 4));
                bf[ni][ks] = *(short8*)((char*)Bs + byte);
            }
#pragma unroll
        for (int mi = 0; mi < 2; ++mi)
#pragma unroll
            for (int ni = 0; ni < 4; ++ni)
#pragma unroll
                for (int ks = 0; ks < 2; ++ks)
                    acc[mi][ni] = __builtin_amdgcn_mfma_f32_16x16x32_bf16(
                        af[mi][ks], bf[ni][ks], acc[mi][ni], 0, 0, 0);
        __syncthreads();
    }

    // ---- epilogue: D frag mapping col=lane&15, row=(lane>>4)*4+reg
#pragma unroll
    for (int mi = 0; mi < 2; ++mi) {
        int rb = row0 + wm * 32 + mi * 16 + (l >> 4) * 4;
        float dv[4];
#pragma unroll
        for (int reg = 0; reg < 4; ++reg)
            dv[reg] = (rb + reg < n) ? dinv[rb + reg] : 0.f;
#pragma unroll
        for (int ni = 0; ni < 4; ++ni) {
            int col = wn * 64 + ni * 16 + (l & 15);
#pragma unroll
            for (int reg = 0; reg < 4; ++reg) {
                int row = rb + reg;
                if (row < n) hs[(long)row * F_HID + col] = acc[mi][ni][reg] * dv[reg];
            }
        }
    }
}

// ---------------- gather layer 1 + epilogue: h1 = relu(dinv * (hs[self]+sum hs[src]) + b1) ----------------
__global__ __launch_bounds__(256) void k_gather1(const float* __restrict__ hs,
                                                 const int* __restrict__ rowptr,
                                                 const int* __restrict__ csr,
                                                 const float* __restrict__ dinv,
                                                 const float* __restrict__ b1,
                                                 float* __restrict__ h1, int n) {
    int tid = blockIdx.x * 256 + threadIdx.x;
    int node = tid >> 5;
    if (node >= n) return;
    int q = (tid & 31) * 4;
    float4 v = *(const float4*)&hs[(long)node * F_HID + q];  // self-loop
    int lo = rowptr[node], hi = rowptr[node + 1];
    for (int e = lo; e < hi; ++e) {
        int s = csr[e];
        float4 u = *(const float4*)&hs[(long)s * F_HID + q];
        v.x += u.x; v.y += u.y; v.z += u.z; v.w += u.w;
    }
    float dv = dinv[node];
    float4 bb = *(const float4*)&b1[q];
    *(float4*)&h1[(long)node * F_HID + q] =
        make_float4(fmaxf(dv * v.x + bb.x, 0.f), fmaxf(dv * v.y + bb.y, 0.f),
                    fmaxf(dv * v.z + bb.z, 0.f), fmaxf(dv * v.w + bb.w, 0.f));
}

// ---------------- GEMM2: hs2 = (h1 @ W2) * dinv ----------------
__global__ __launch_bounds__(256) void k_gemm2(const float* __restrict__ h1,
                                               const float* __restrict__ W2,
                                               const float* __restrict__ dinv,
                                               float* __restrict__ hs2, int n) {
    __shared__ float w2s[F_HID * F_OUT];
    __shared__ float rs[4][F_HID];
    for (int i = threadIdx.x; i < F_HID * F_OUT; i += 256) w2s[i] = W2[i];
    int w = threadIdx.x >> 6, lane = threadIdx.x & 63;
    int node = blockIdx.x * 4 + w;
    if (node < n) {
        for (int k = lane; k < F_HID; k += 64)
            rs[w][k] = h1[(long)node * F_HID + k];
    }
    __syncthreads();
    if (node < n && lane < F_OUT) {
        float s = 0.f;
#pragma unroll 8
        for (int k = 0; k < F_HID; ++k) s += rs[w][k] * w2s[k * F_OUT + lane];
        hs2[(long)node * F_OUT + lane] = s * dinv[node];
    }
}

// ---------------- gather layer 2 + bias + log_softmax ----------------
__global__ __launch_bounds__(256) void k_out(const float* __restrict__ hs2,
                                             const int* __restrict__ rowptr,
                                             const int* __restrict__ csr,
                                             const float* __restrict__ dinv,
                                             const float* __restrict__ b2,
                                             float* __restrict__ out, int n) {
    int w = threadIdx.x >> 6, lane = threadIdx.x & 63;
    int node = blockIdx.x * 4 + w;
    if (node >= n) return;
    float v = (lane < F_OUT) ? hs2[(long)node * F_OUT + lane] : 0.f;  // self-loop
    int lo = rowptr[node], hi = rowptr[node + 1];
    for (int e = lo; e < hi; ++e) {
        int s = csr[e];
        if (lane < F_OUT) v += hs2[(long)s * F_OUT + lane];
    }
    float z = (lane < F_OUT) ? v * dinv[node] + b2[lane] : -INFINITY;
    float m = z;
#pragma unroll
    for (int o = 32; o; o >>= 1) m = fmaxf(m, __shfl_xor(m, o));
    float ev = (lane < F_OUT) ? __expf(z - m) : 0.f;
    float sum = ev;
#pragma unroll
    for (int o = 32; o; o >>= 1) sum += __shfl_xor(sum, o);
    float ls = logf(sum);
    if (lane < F_OUT) out[(long)node * F_OUT + lane] = z - m - ls;
}

extern "C" void kernel_launch(void* const* d_in, const int* in_sizes, int n_in,
                              void* d_out, int out_size, void* d_ws, size_t ws_size,
                              hipStream_t stream) {
    const float* x  = (const float*)d_in[0];
    const float* W1 = (const float*)d_in[1];
    const float* b1 = (const float*)d_in[2];
    const float* W2 = (const float*)d_in[3];
    const float* b2 = (const float*)d_in[4];
    const int*   ei = (const int*)d_in[5];

    int n = in_sizes[0] / F_IN;      // 50000
    int E = in_sizes[5] / 2;         // 800000
    float* out = (float*)d_out;

    // workspace layout
    char* ws = (char*)d_ws;
    float* dinv   = (float*)(ws + 0);          // 200 KB
    int*   ecnt   = (int*)  (ws + 200704);
    int*   rowptr = (int*)  (ws + 401408);     // n+1 ints
    int*   cur    = (int*)  (ws + 602112);     // dead after k_fill; Btg aliases it
    unsigned short* Btg = (unsigned short*)(ws + 602112);  // 128*512*2 = 128 KB
    int*   csr    = (int*)  (ws + 802816);     // E ints = 3.2 MB
    float* hs     = (float*)(ws + 4003840);    // 25.6 MB
    float* h1     = (float*)(ws + 29603840);   // 25.6 MB
    float* hs2    = hs;                         // alias: hs dead after k_gather1

    int nb = (n + 255) / 256;
    int eb = (E + 255) / 256;
    k_zero<<<nb, 256, 0, stream>>>(ecnt, n);
    k_deg_count<<<eb, 256, 0, stream>>>(ei, ecnt, E);
    k_dinv<<<nb, 256, 0, stream>>>(ecnt, dinv, n);
    k_scan<<<1, 1024, 0, stream>>>(ecnt, rowptr, cur, n);
    k_fill<<<eb, 256, 0, stream>>>(ei, cur, csr, E);
    // cur is dead from here; Btg reuses its storage (stream-ordered)
    k_w1cvt<<<256, 256, 0, stream>>>(W1, Btg);

    k_gemm1_mfma<<<(n + BM - 1) / BM, 256, 0, stream>>>(x, Btg, dinv, hs, n);
    k_gather1<<<(n * 32 + 255) / 256, 256, 0, stream>>>(hs, rowptr, csr, dinv, b1, h1, n);
    k_gemm2<<<(n + 3) / 4, 256, 0, stream>>>(h1, W2, dinv, hs2, n);
    k_out<<<(n + 3) / 4, 256, 0, stream>>>(hs2, rowptr, csr, dinv, b2, out, n);
}

// Round 4
// 333.810 us; speedup vs baseline: 5.4541x; 1.3138x over previous
//
#include <hip/hip_runtime.h>
#include <math.h>

#define F_IN 500
#define F_HID 128
#define F_OUT 47

typedef __attribute__((ext_vector_type(8))) short short8;
typedef __attribute__((ext_vector_type(4))) float f32x4;

__device__ inline unsigned pack_bf16x2(float a, float b) {
    unsigned ua = __float_as_uint(a), ub = __float_as_uint(b);
    ua = (ua + 0x7FFFu + ((ua >> 16) & 1u)) >> 16;
    ub = (ub + 0x7FFFu + ((ub >> 16) & 1u)) >> 16;
    return ua | (ub << 16);
}

// ---------------- degree / norm / CSR build ----------------
__global__ void k_zero(int* __restrict__ p, int n) {
    int i = blockIdx.x * 256 + threadIdx.x;
    if (i < n) p[i] = 0;
}

__global__ void k_deg_count(const int* __restrict__ ei, int* __restrict__ ecnt, int E) {
    int e = blockIdx.x * 256 + threadIdx.x;
    if (e < E) atomicAdd(&ecnt[ei[E + e]], 1);  // dst = ei[1][e]
}

__global__ void k_dinv(const int* __restrict__ ecnt, float* __restrict__ dinv, int n) {
    int i = blockIdx.x * 256 + threadIdx.x;
    if (i < n) dinv[i] = rsqrtf((float)(ecnt[i] + 1));  // +1 self-loop
}

// ---------------- 3-phase device-wide exclusive scan (n=50000, nb=49 blocks) ----------------
__global__ __launch_bounds__(1024) void k_scanA(const int* __restrict__ ecnt,
                                                int* __restrict__ rowptr,
                                                int* __restrict__ bsum, int n) {
    __shared__ int tmp[1024];
    int t = threadIdx.x;
    int gid = blockIdx.x * 1024 + t;
    int v = (gid < n) ? ecnt[gid] : 0;
    tmp[t] = v;
    __syncthreads();
    for (int off = 1; off < 1024; off <<= 1) {
        int u = (t >= off) ? tmp[t - off] : 0;
        __syncthreads();
        tmp[t] += u;
        __syncthreads();
    }
    if (gid < n) rowptr[gid] = tmp[t] - v;     // exclusive within block
    if (t == 1023) bsum[blockIdx.x] = tmp[1023];
}

// one wave (64 lanes) scans block sums; requires nb <= 64 (nb=49 here)
__global__ void k_scanB(const int* __restrict__ bsum, int* __restrict__ boffs, int nb) {
    int t = threadIdx.x;
    int v = (t < nb) ? bsum[t] : 0;
    int inc = v;
#pragma unroll
    for (int off = 1; off < 64; off <<= 1) {
        int u = __shfl_up(inc, off);
        if (t >= off) inc += u;
    }
    if (t < nb) boffs[t] = inc - v;            // exclusive block offsets
    if (t == nb - 1) boffs[nb] = inc;          // grand total
}

__global__ __launch_bounds__(1024) void k_scanC(int* __restrict__ rowptr,
                                                int* __restrict__ cur,
                                                const int* __restrict__ boffs,
                                                int n, int nb) {
    int gid = blockIdx.x * 1024 + threadIdx.x;
    if (gid < n) {
        int v = rowptr[gid] + boffs[blockIdx.x];
        rowptr[gid] = v;
        cur[gid] = v;
    } else if (gid == n) {
        rowptr[n] = boffs[nb];
    }
}

__global__ void k_fill(const int* __restrict__ ei, int* __restrict__ cur,
                       int* __restrict__ csr, int E) {
    int e = blockIdx.x * 256 + threadIdx.x;
    if (e < E) {
        int d = ei[E + e];
        int pos = atomicAdd(&cur[d], 1);
        csr[pos] = ei[e];  // src
    }
}

// ---------------- W1 -> bf16, transposed [128 cols][512 k] (k padded w/ zeros) ----------------
__global__ void k_w1cvt(const float* __restrict__ W1, unsigned short* __restrict__ Btg) {
    int id = blockIdx.x * 256 + threadIdx.x;  // 65536 total
    int kk = id >> 7, c = id & 127;
    float v = (kk < F_IN) ? W1[kk * F_HID + c] : 0.f;
    unsigned u = __float_as_uint(v);
    u = (u + 0x7FFFu + ((u >> 16) & 1u)) >> 16;
    Btg[c * 512 + kk] = (unsigned short)u;
}

// ---------------- GEMM1 (bf16 MFMA): hs = (x @ W1) * dinv ----------------
// BM=64 rows/block, BK=64, 256 thr = 4 waves (2x2), wave tile 32x64.
#define BM 64
#define BK 64
__global__ __launch_bounds__(256) void k_gemm1_mfma(const float* __restrict__ x,
                                                    const unsigned short* __restrict__ Btg,
                                                    const float* __restrict__ dinv,
                                                    float* __restrict__ hs, int n) {
    __shared__ unsigned short As[BM * BK];    // XOR-swizzled
    __shared__ unsigned short Bs[F_HID * BK]; // XOR-swizzled (B stored col-major: [col][k])
    int t = threadIdx.x;
    int row0 = blockIdx.x * BM;
    int w = t >> 6, l = t & 63;
    int wm = w >> 1, wn = w & 1;  // wave rows: wm*32.., wave cols: wn*64..

    f32x4 acc[2][4] = {};

    for (int c = 0; c < 8; ++c) {
        int k0 = c * BK;
        // ---- stage A: 64x64 fp32 -> bf16 LDS (2 units of 8 elems per thread)
#pragma unroll
        for (int uu = 0; uu < 2; ++uu) {
            int u = t + uu * 256;            // 0..511
            int r = u >> 3, cg = u & 7;
            int grow = row0 + r;
            int kbase = k0 + cg * 8;
            float4 f0 = make_float4(0.f, 0.f, 0.f, 0.f);
            float4 f1 = make_float4(0.f, 0.f, 0.f, 0.f);
            if (grow < n) {
                const float* p = x + (long)grow * F_IN + kbase;
                if (kbase + 4 <= F_IN) f0 = *(const float4*)p;
                if (kbase + 8 <= F_IN) f1 = *(const float4*)(p + 4);
            }
            uint4 pk;
            pk.x = pack_bf16x2(f0.x, f0.y);
            pk.y = pack_bf16x2(f0.z, f0.w);
            pk.z = pack_bf16x2(f1.x, f1.y);
            pk.w = pack_bf16x2(f1.z, f1.w);
            int byte = r * 128 + ((cg * 16) ^ ((r & 7) << 4));
            *(uint4*)((char*)As + byte) = pk;
        }
        // ---- stage B: 128 cols x 64 k bf16 (4 units of 8 elems per thread)
#pragma unroll
        for (int uu = 0; uu < 4; ++uu) {
            int u = t + uu * 256;            // 0..1023
            int r = u >> 3, cg = u & 7;      // r = col index 0..127
            uint4 v = *(const uint4*)(Btg + r * 512 + k0 + cg * 8);
            int byte = r * 128 + ((cg * 16) ^ ((r & 7) << 4));
            *(uint4*)((char*)Bs + byte) = v;
        }
        __syncthreads();

        // ---- fragments + MFMA
        int lr = l & 15;
        int lkb = (l >> 4) * 16;  // byte offset of this lane's 8-elem k group
        short8 af[2][2], bf[4][2];
#pragma unroll
        for (int mi = 0; mi < 2; ++mi)
#pragma unroll
            for (int ks = 0; ks < 2; ++ks) {
                int r = wm * 32 + mi * 16 + lr;
                int byte = r * 128 + (((ks * 64) + lkb) ^ ((r & 7) << 4));
                af[mi][ks] = *(short8*)((char*)As + byte);
            }
#pragma unroll
        for (int ni = 0; ni < 4; ++ni)
#pragma unroll
            for (int ks = 0; ks < 2; ++ks) {
                int r = wn * 64 + ni * 16 + lr;
                int byte = r * 128 + (((ks * 64) + lkb) ^ ((r & 7) << 4));
                bf[ni][ks] = *(short8*)((char*)Bs + byte);
            }
#pragma unroll
        for (int mi = 0; mi < 2; ++mi)
#pragma unroll
            for (int ni = 0; ni < 4; ++ni)
#pragma unroll
                for (int ks = 0; ks < 2; ++ks)
                    acc[mi][ni] = __builtin_amdgcn_mfma_f32_16x16x32_bf16(
                        af[mi][ks], bf[ni][ks], acc[mi][ni], 0, 0, 0);
        __syncthreads();
    }

    // ---- epilogue: D frag mapping col=lane&15, row=(lane>>4)*4+reg
#pragma unroll
    for (int mi = 0; mi < 2; ++mi) {
        int rb = row0 + wm * 32 + mi * 16 + (l >> 4) * 4;
        float dv[4];
#pragma unroll
        for (int reg = 0; reg < 4; ++reg)
            dv[reg] = (rb + reg < n) ? dinv[rb + reg] : 0.f;
#pragma unroll
        for (int ni = 0; ni < 4; ++ni) {
            int col = wn * 64 + ni * 16 + (l & 15);
#pragma unroll
            for (int reg = 0; reg < 4; ++reg) {
                int row = rb + reg;
                if (row < n) hs[(long)row * F_HID + col] = acc[mi][ni][reg] * dv[reg];
            }
        }
    }
}

// ---------------- gather layer 1 + epilogue: h1 = relu(dinv * (hs[self]+sum hs[src]) + b1) ----------------
__global__ __launch_bounds__(256) void k_gather1(const float* __restrict__ hs,
                                                 const int* __restrict__ rowptr,
                                                 const int* __restrict__ csr,
                                                 const float* __restrict__ dinv,
                                                 const float* __restrict__ b1,
                                                 float* __restrict__ h1, int n) {
    int tid = blockIdx.x * 256 + threadIdx.x;
    int node = tid >> 5;
    if (node >= n) return;
    int q = (tid & 31) * 4;
    float4 v = *(const float4*)&hs[(long)node * F_HID + q];  // self-loop
    int lo = rowptr[node], hi = rowptr[node + 1];
    for (int e = lo; e < hi; ++e) {
        int s = csr[e];
        float4 u = *(const float4*)&hs[(long)s * F_HID + q];
        v.x += u.x; v.y += u.y; v.z += u.z; v.w += u.w;
    }
    float dv = dinv[node];
    float4 bb = *(const float4*)&b1[q];
    *(float4*)&h1[(long)node * F_HID + q] =
        make_float4(fmaxf(dv * v.x + bb.x, 0.f), fmaxf(dv * v.y + bb.y, 0.f),
                    fmaxf(dv * v.z + bb.z, 0.f), fmaxf(dv * v.w + bb.w, 0.f));
}

// ---------------- GEMM2: hs2 = (h1 @ W2) * dinv ----------------
__global__ __launch_bounds__(256) void k_gemm2(const float* __restrict__ h1,
                                               const float* __restrict__ W2,
                                               const float* __restrict__ dinv,
                                               float* __restrict__ hs2, int n) {
    __shared__ float w2s[F_HID * F_OUT];
    __shared__ float rs[4][F_HID];
    for (int i = threadIdx.x; i < F_HID * F_OUT; i += 256) w2s[i] = W2[i];
    int w = threadIdx.x >> 6, lane = threadIdx.x & 63;
    int node = blockIdx.x * 4 + w;
    if (node < n) {
        for (int k = lane; k < F_HID; k += 64)
            rs[w][k] = h1[(long)node * F_HID + k];
    }
    __syncthreads();
    if (node < n && lane < F_OUT) {
        float s = 0.f;
#pragma unroll 8
        for (int k = 0; k < F_HID; ++k) s += rs[w][k] * w2s[k * F_OUT + lane];
        hs2[(long)node * F_OUT + lane] = s * dinv[node];
    }
}

// ---------------- gather layer 2 + bias + log_softmax ----------------
__global__ __launch_bounds__(256) void k_out(const float* __restrict__ hs2,
                                             const int* __restrict__ rowptr,
                                             const int* __restrict__ csr,
                                             const float* __restrict__ dinv,
                                             const float* __restrict__ b2,
                                             float* __restrict__ out, int n) {
    int w = threadIdx.x >> 6, lane = threadIdx.x & 63;
    int node = blockIdx.x * 4 + w;
    if (node >= n) return;
    float v = (lane < F_OUT) ? hs2[(long)node * F_OUT + lane] : 0.f;  // self-loop
    int lo = rowptr[node], hi = rowptr[node + 1];
    for (int e = lo; e < hi; ++e) {
        int s = csr[e];
        if (lane < F_OUT) v += hs2[(long)s * F_OUT + lane];
    }
    float z = (lane < F_OUT) ? v * dinv[node] + b2[lane] : -INFINITY;
    float m = z;
#pragma unroll
    for (int o = 32; o; o >>= 1) m = fmaxf(m, __shfl_xor(m, o));
    float ev = (lane < F_OUT) ? __expf(z - m) : 0.f;
    float sum = ev;
#pragma unroll
    for (int o = 32; o; o >>= 1) sum += __shfl_xor(sum, o);
    float ls = logf(sum);
    if (lane < F_OUT) out[(long)node * F_OUT + lane] = z - m - ls;
}

extern "C" void kernel_launch(void* const* d_in, const int* in_sizes, int n_in,
                              void* d_out, int out_size, void* d_ws, size_t ws_size,
                              hipStream_t stream) {
    const float* x  = (const float*)d_in[0];
    const float* W1 = (const float*)d_in[1];
    const float* b1 = (const float*)d_in[2];
    const float* W2 = (const float*)d_in[3];
    const float* b2 = (const float*)d_in[4];
    const int*   ei = (const int*)d_in[5];

    int n = in_sizes[0] / F_IN;      // 50000
    int E = in_sizes[5] / 2;         // 800000
    float* out = (float*)d_out;

    // workspace layout
    char* ws = (char*)d_ws;
    float* dinv   = (float*)(ws + 0);          // 200 KB
    int*   ecnt   = (int*)  (ws + 200704);     // dead after scanA
    int*   rowptr = (int*)  (ws + 401408);     // n+1 ints
    int*   cur    = (int*)  (ws + 602112);     // dead after k_fill; Btg aliases it
    unsigned short* Btg = (unsigned short*)(ws + 602112);  // 128*512*2 = 128 KB (ends 733184)
    int*   bsum   = (int*)  (ws + 733184);     // 49 ints  (slack before csr)
    int*   boffs  = (int*)  (ws + 737280);     // 50 ints
    int*   csr    = (int*)  (ws + 802816);     // E ints = 3.2 MB
    float* hs     = (float*)(ws + 4003840);    // 25.6 MB
    float* h1     = (float*)(ws + 29603840);   // 25.6 MB
    float* hs2    = hs;                         // alias: hs dead after k_gather1

    int nb = (n + 255) / 256;
    int eb = (E + 255) / 256;
    int sb = (n + 1023) / 1024;                 // 49 scan blocks (<=64 required by k_scanB)
    k_zero<<<nb, 256, 0, stream>>>(ecnt, n);
    k_deg_count<<<eb, 256, 0, stream>>>(ei, ecnt, E);
    k_dinv<<<nb, 256, 0, stream>>>(ecnt, dinv, n);
    k_scanA<<<sb, 1024, 0, stream>>>(ecnt, rowptr, bsum, n);
    k_scanB<<<1, 64, 0, stream>>>(bsum, boffs, sb);
    k_scanC<<<sb, 1024, 0, stream>>>(rowptr, cur, boffs, n, sb);
    k_fill<<<eb, 256, 0, stream>>>(ei, cur, csr, E);
    // cur is dead from here; Btg reuses its storage (stream-ordered)
    k_w1cvt<<<256, 256, 0, stream>>>(W1, Btg);

    k_gemm1_mfma<<<(n + BM - 1) / BM, 256, 0, stream>>>(x, Btg, dinv, hs, n);
    k_gather1<<<(n * 32 + 255) / 256, 256, 0, stream>>>(hs, rowptr, csr, dinv, b1, h1, n);
    k_gemm2<<<(n + 3) / 4, 256, 0, stream>>>(h1, W2, dinv, hs2, n);
    k_out<<<(n + 3) / 4, 256, 0, stream>>>(hs2, rowptr, csr, dinv, b2, out, n);
}

// Round 5
// 295.533 us; speedup vs baseline: 6.1605x; 1.1295x over previous
//
#include <hip/hip_runtime.h>
#include <math.h>

#define F_IN 500
#define F_HID 128
#define F_OUT 47

typedef __attribute__((ext_vector_type(8))) short short8;
typedef __attribute__((ext_vector_type(4))) float f32x4;

__device__ inline unsigned pack_bf16x2(float a, float b) {
    unsigned ua = __float_as_uint(a), ub = __float_as_uint(b);
    ua = (ua + 0x7FFFu + ((ua >> 16) & 1u)) >> 16;
    ub = (ub + 0x7FFFu + ((ub >> 16) & 1u)) >> 16;
    return ua | (ub << 16);
}
__device__ inline unsigned short pack_bf16(float a) {
    unsigned u = __float_as_uint(a);
    return (unsigned short)((u + 0x7FFFu + ((u >> 16) & 1u)) >> 16);
}

// ---------------- degree / norm / CSR build ----------------
__global__ void k_zero(int* __restrict__ p, int n) {
    int i = blockIdx.x * 256 + threadIdx.x;
    if (i < n) p[i] = 0;
}

__global__ void k_deg_count(const int* __restrict__ ei, int* __restrict__ ecnt, int E) {
    int e = blockIdx.x * 256 + threadIdx.x;
    if (e < E) atomicAdd(&ecnt[ei[E + e]], 1);  // dst = ei[1][e]
}

__global__ void k_dinv(const int* __restrict__ ecnt, float* __restrict__ dinv, int n) {
    int i = blockIdx.x * 256 + threadIdx.x;
    if (i < n) dinv[i] = rsqrtf((float)(ecnt[i] + 1));  // +1 self-loop
}

// ---------------- 3-phase device-wide exclusive scan ----------------
__global__ __launch_bounds__(1024) void k_scanA(const int* __restrict__ ecnt,
                                                int* __restrict__ rowptr,
                                                int* __restrict__ bsum, int n) {
    __shared__ int tmp[1024];
    int t = threadIdx.x;
    int gid = blockIdx.x * 1024 + t;
    int v = (gid < n) ? ecnt[gid] : 0;
    tmp[t] = v;
    __syncthreads();
    for (int off = 1; off < 1024; off <<= 1) {
        int u = (t >= off) ? tmp[t - off] : 0;
        __syncthreads();
        tmp[t] += u;
        __syncthreads();
    }
    if (gid < n) rowptr[gid] = tmp[t] - v;
    if (t == 1023) bsum[blockIdx.x] = tmp[1023];
}

__global__ void k_scanB(const int* __restrict__ bsum, int* __restrict__ boffs, int nb) {
    int t = threadIdx.x;
    int v = (t < nb) ? bsum[t] : 0;
    int inc = v;
#pragma unroll
    for (int off = 1; off < 64; off <<= 1) {
        int u = __shfl_up(inc, off);
        if (t >= off) inc += u;
    }
    if (t < nb) boffs[t] = inc - v;
    if (t == nb - 1) boffs[nb] = inc;
}

__global__ __launch_bounds__(1024) void k_scanC(int* __restrict__ rowptr,
                                                int* __restrict__ cur,
                                                const int* __restrict__ boffs,
                                                int n, int nb) {
    int gid = blockIdx.x * 1024 + threadIdx.x;
    if (gid < n) {
        int v = rowptr[gid] + boffs[blockIdx.x];
        rowptr[gid] = v;
        cur[gid] = v;
    } else if (gid == n) {
        rowptr[n] = boffs[nb];
    }
}

__global__ void k_fill(const int* __restrict__ ei, int* __restrict__ cur,
                       int* __restrict__ csr, int E) {
    int e = blockIdx.x * 256 + threadIdx.x;
    if (e < E) {
        int d = ei[E + e];
        int pos = atomicAdd(&cur[d], 1);
        csr[pos] = ei[e];  // src
    }
}

// ---------------- W1 -> bf16, transposed [128 cols][512 k] ----------------
__global__ void k_w1cvt(const float* __restrict__ W1, unsigned short* __restrict__ Btg) {
    int id = blockIdx.x * 256 + threadIdx.x;  // 65536 total
    int kk = id >> 7, c = id & 127;
    float v = (kk < F_IN) ? W1[kk * F_HID + c] : 0.f;
    Btg[c * 512 + kk] = pack_bf16(v);
}

// ---------------- GEMM1 (bf16 MFMA): hs16 = bf16((x @ W1) * dinv) ----------------
#define BM 64
#define BK 64
__global__ __launch_bounds__(256) void k_gemm1_mfma(const float* __restrict__ x,
                                                    const unsigned short* __restrict__ Btg,
                                                    const float* __restrict__ dinv,
                                                    unsigned short* __restrict__ hs16, int n) {
    __shared__ unsigned short As[BM * BK];
    __shared__ unsigned short Bs[F_HID * BK];
    int t = threadIdx.x;
    int row0 = blockIdx.x * BM;
    int w = t >> 6, l = t & 63;
    int wm = w >> 1, wn = w & 1;

    f32x4 acc[2][4] = {};

    for (int c = 0; c < 8; ++c) {
        int k0 = c * BK;
#pragma unroll
        for (int uu = 0; uu < 2; ++uu) {
            int u = t + uu * 256;
            int r = u >> 3, cg = u & 7;
            int grow = row0 + r;
            int kbase = k0 + cg * 8;
            float4 f0 = make_float4(0.f, 0.f, 0.f, 0.f);
            float4 f1 = make_float4(0.f, 0.f, 0.f, 0.f);
            if (grow < n) {
                const float* p = x + (long)grow * F_IN + kbase;
                if (kbase + 4 <= F_IN) f0 = *(const float4*)p;
                if (kbase + 8 <= F_IN) f1 = *(const float4*)(p + 4);
            }
            uint4 pk;
            pk.x = pack_bf16x2(f0.x, f0.y);
            pk.y = pack_bf16x2(f0.z, f0.w);
            pk.z = pack_bf16x2(f1.x, f1.y);
            pk.w = pack_bf16x2(f1.z, f1.w);
            int byte = r * 128 + ((cg * 16) ^ ((r & 7) << 4));
            *(uint4*)((char*)As + byte) = pk;
        }
#pragma unroll
        for (int uu = 0; uu < 4; ++uu) {
            int u = t + uu * 256;
            int r = u >> 3, cg = u & 7;
            uint4 v = *(const uint4*)(Btg + r * 512 + k0 + cg * 8);
            int byte = r * 128 + ((cg * 16) ^ ((r & 7) << 4));
            *(uint4*)((char*)Bs + byte) = v;
        }
        __syncthreads();

        int lr = l & 15;
        int lkb = (l >> 4) * 16;
        short8 af[2][2], bf[4][2];
#pragma unroll
        for (int mi = 0; mi < 2; ++mi)
#pragma unroll
            for (int ks = 0; ks < 2; ++ks) {
                int r = wm * 32 + mi * 16 + lr;
                int byte = r * 128 + (((ks * 64) + lkb) ^ ((r & 7) << 4));
                af[mi][ks] = *(short8*)((char*)As + byte);
            }
#pragma unroll
        for (int ni = 0; ni < 4; ++ni)
#pragma unroll
            for (int ks = 0; ks < 2; ++ks) {
                int r = wn * 64 + ni * 16 + lr;
                int byte = r * 128 + (((ks * 64) + lkb) ^ ((r & 7) << 4));
                bf[ni][ks] = *(short8*)((char*)Bs + byte);
            }
#pragma unroll
        for (int mi = 0; mi < 2; ++mi)
#pragma unroll
            for (int ni = 0; ni < 4; ++ni)
#pragma unroll
                for (int ks = 0; ks < 2; ++ks)
                    acc[mi][ni] = __builtin_amdgcn_mfma_f32_16x16x32_bf16(
                        af[mi][ks], bf[ni][ks], acc[mi][ni], 0, 0, 0);
        __syncthreads();
    }

    // epilogue: col=lane&15, row=(lane>>4)*4+reg ; write bf16
#pragma unroll
    for (int mi = 0; mi < 2; ++mi) {
        int rb = row0 + wm * 32 + mi * 16 + (l >> 4) * 4;
        float dv[4];
#pragma unroll
        for (int reg = 0; reg < 4; ++reg)
            dv[reg] = (rb + reg < n) ? dinv[rb + reg] : 0.f;
#pragma unroll
        for (int ni = 0; ni < 4; ++ni) {
            int col = wn * 64 + ni * 16 + (l & 15);
#pragma unroll
            for (int reg = 0; reg < 4; ++reg) {
                int row = rb + reg;
                if (row < n) hs16[(long)row * F_HID + col] = pack_bf16(acc[mi][ni][reg] * dv[reg]);
            }
        }
    }
}

// ---------------- gather layer 1: h1 = relu(dinv * (hs16[self]+sum hs16[src]) + b1) ----------------
// half-wave (32 lanes) per node; lane q holds 4 bf16 cols (uint2 = 8B), fp32 accum
__global__ __launch_bounds__(256) void k_gather1(const unsigned short* __restrict__ hs16,
                                                 const int* __restrict__ rowptr,
                                                 const int* __restrict__ csr,
                                                 const float* __restrict__ dinv,
                                                 const float* __restrict__ b1,
                                                 float* __restrict__ h1, int n) {
    int tid = blockIdx.x * 256 + threadIdx.x;
    int node = tid >> 5;
    if (node >= n) return;
    int q = tid & 31;
    float4 v = make_float4(0.f, 0.f, 0.f, 0.f);
    {
        uint2 u = *(const uint2*)(hs16 + (long)node * F_HID + q * 4);  // self
        v.x = __uint_as_float(u.x << 16);
        v.y = __uint_as_float(u.x & 0xFFFF0000u);
        v.z = __uint_as_float(u.y << 16);
        v.w = __uint_as_float(u.y & 0xFFFF0000u);
    }
    int lo = rowptr[node], hi = rowptr[node + 1];
    for (int e = lo; e < hi; ++e) {
        int s = csr[e];
        uint2 u = *(const uint2*)(hs16 + (long)s * F_HID + q * 4);
        v.x += __uint_as_float(u.x << 16);
        v.y += __uint_as_float(u.x & 0xFFFF0000u);
        v.z += __uint_as_float(u.y << 16);
        v.w += __uint_as_float(u.y & 0xFFFF0000u);
    }
    float dv = dinv[node];
    float4 bb = *(const float4*)&b1[q * 4];
    *(float4*)&h1[(long)node * F_HID + q * 4] =
        make_float4(fmaxf(dv * v.x + bb.x, 0.f), fmaxf(dv * v.y + bb.y, 0.f),
                    fmaxf(dv * v.z + bb.z, 0.f), fmaxf(dv * v.w + bb.w, 0.f));
}

// ---------------- GEMM2: hs2_16 = bf16((h1 @ W2) * dinv), padded to 64 cols ----------------
__global__ __launch_bounds__(256) void k_gemm2(const float* __restrict__ h1,
                                               const float* __restrict__ W2,
                                               const float* __restrict__ dinv,
                                               unsigned short* __restrict__ hs2, int n) {
    __shared__ float w2s[F_HID * F_OUT];
    __shared__ float rs[4][F_HID];
    for (int i = threadIdx.x; i < F_HID * F_OUT; i += 256) w2s[i] = W2[i];
    int w = threadIdx.x >> 6, lane = threadIdx.x & 63;
    int node = blockIdx.x * 4 + w;
    if (node < n) {
        for (int k = lane; k < F_HID; k += 64)
            rs[w][k] = h1[(long)node * F_HID + k];
    }
    __syncthreads();
    if (node < n) {
        float v = 0.f;
        if (lane < F_OUT) {
            float s = 0.f;
#pragma unroll 8
            for (int k = 0; k < F_HID; ++k) s += rs[w][k] * w2s[k * F_OUT + lane];
            v = s * dinv[node];
        }
        hs2[(long)node * 64 + lane] = pack_bf16(v);  // pad cols 47..63 = 0
    }
}

// ---------------- gather layer 2 + bias + log_softmax ----------------
// half-wave per node; lane q holds cols {2q, 2q+1}; row = one 128B cacheline
__global__ __launch_bounds__(256) void k_out(const unsigned short* __restrict__ hs2,
                                             const int* __restrict__ rowptr,
                                             const int* __restrict__ csr,
                                             const float* __restrict__ dinv,
                                             const float* __restrict__ b2,
                                             float* __restrict__ out, int n) {
    int tid = blockIdx.x * 256 + threadIdx.x;
    int node = tid >> 5;
    if (node >= n) return;
    int q = tid & 31;
    int c0 = 2 * q, c1 = 2 * q + 1;
    float v0, v1;
    {
        unsigned u = *(const unsigned*)(hs2 + (long)node * 64 + c0);  // self
        v0 = __uint_as_float(u << 16);
        v1 = __uint_as_float(u & 0xFFFF0000u);
    }
    int lo = rowptr[node], hi = rowptr[node + 1];
    for (int e = lo; e < hi; ++e) {
        int s = csr[e];
        unsigned u = *(const unsigned*)(hs2 + (long)s * 64 + c0);
        v0 += __uint_as_float(u << 16);
        v1 += __uint_as_float(u & 0xFFFF0000u);
    }
    float dv = dinv[node];
    float z0 = (c0 < F_OUT) ? v0 * dv + b2[c0] : -INFINITY;
    float z1 = (c1 < F_OUT) ? v1 * dv + b2[c1] : -INFINITY;
    float m = fmaxf(z0, z1);
#pragma unroll
    for (int o = 16; o; o >>= 1) m = fmaxf(m, __shfl_xor(m, o));
    float sum = ((c0 < F_OUT) ? __expf(z0 - m) : 0.f) + ((c1 < F_OUT) ? __expf(z1 - m) : 0.f);
#pragma unroll
    for (int o = 16; o; o >>= 1) sum += __shfl_xor(sum, o);
    float ls = logf(sum) + m;
    if (c0 < F_OUT) out[(long)node * F_OUT + c0] = z0 - ls;
    if (c1 < F_OUT) out[(long)node * F_OUT + c1] = z1 - ls;
}

extern "C" void kernel_launch(void* const* d_in, const int* in_sizes, int n_in,
                              void* d_out, int out_size, void* d_ws, size_t ws_size,
                              hipStream_t stream) {
    const float* x  = (const float*)d_in[0];
    const float* W1 = (const float*)d_in[1];
    const float* b1 = (const float*)d_in[2];
    const float* W2 = (const float*)d_in[3];
    const float* b2 = (const float*)d_in[4];
    const int*   ei = (const int*)d_in[5];

    int n = in_sizes[0] / F_IN;      // 50000
    int E = in_sizes[5] / 2;         // 800000
    float* out = (float*)d_out;

    // workspace layout
    char* ws = (char*)d_ws;
    float* dinv   = (float*)(ws + 0);          // 200 KB
    int*   ecnt   = (int*)  (ws + 200704);
    int*   rowptr = (int*)  (ws + 401408);     // n+1 ints
    int*   cur    = (int*)  (ws + 602112);     // dead after k_fill; Btg aliases it
    unsigned short* Btg = (unsigned short*)(ws + 602112);  // 128 KB (ends 733184)
    int*   bsum   = (int*)  (ws + 733184);
    int*   boffs  = (int*)  (ws + 737280);
    int*   csr    = (int*)  (ws + 802816);     // 3.2 MB
    unsigned short* hs16  = (unsigned short*)(ws + 4003840);   // 12.8 MB (ends ~16.8M)
    unsigned short* hs2   = (unsigned short*)(ws + 16804864);  // 6.4 MB
    float* h1     = (float*)(ws + 29603840);   // 25.6 MB

    int nb = (n + 255) / 256;
    int eb = (E + 255) / 256;
    int sb = (n + 1023) / 1024;
    k_zero<<<nb, 256, 0, stream>>>(ecnt, n);
    k_deg_count<<<eb, 256, 0, stream>>>(ei, ecnt, E);
    k_dinv<<<nb, 256, 0, stream>>>(ecnt, dinv, n);
    k_scanA<<<sb, 1024, 0, stream>>>(ecnt, rowptr, bsum, n);
    k_scanB<<<1, 64, 0, stream>>>(bsum, boffs, sb);
    k_scanC<<<sb, 1024, 0, stream>>>(rowptr, cur, boffs, n, sb);
    k_fill<<<eb, 256, 0, stream>>>(ei, cur, csr, E);
    k_w1cvt<<<256, 256, 0, stream>>>(W1, Btg);

    k_gemm1_mfma<<<(n + BM - 1) / BM, 256, 0, stream>>>(x, Btg, dinv, hs16, n);
    k_gather1<<<(n * 32 + 255) / 256, 256, 0, stream>>>(hs16, rowptr, csr, dinv, b1, h1, n);
    k_gemm2<<<(n + 3) / 4, 256, 0, stream>>>(h1, W2, dinv, hs2, n);
    k_out<<<(n * 32 + 255) / 256, 256, 0, stream>>>(hs2, rowptr, csr, dinv, b2, out, n);
}

// Round 6
// 289.672 us; speedup vs baseline: 6.2851x; 1.0202x over previous
//
#include <hip/hip_runtime.h>
#include <math.h>

#define F_IN 500
#define F_HID 128
#define F_OUT 47

typedef __attribute__((ext_vector_type(8))) short short8;
typedef __attribute__((ext_vector_type(4))) float f32x4;

__device__ inline unsigned pack_bf16x2(float a, float b) {
    unsigned ua = __float_as_uint(a), ub = __float_as_uint(b);
    ua = (ua + 0x7FFFu + ((ua >> 16) & 1u)) >> 16;
    ub = (ub + 0x7FFFu + ((ub >> 16) & 1u)) >> 16;
    return ua | (ub << 16);
}
__device__ inline unsigned short pack_bf16(float a) {
    unsigned u = __float_as_uint(a);
    return (unsigned short)((u + 0x7FFFu + ((u >> 16) & 1u)) >> 16);
}

// ---------------- degree / norm / CSR build ----------------
__global__ void k_zero(int* __restrict__ p, int n) {
    int i = blockIdx.x * 256 + threadIdx.x;
    if (i < n) p[i] = 0;
}

__global__ void k_deg_count(const int* __restrict__ ei, int* __restrict__ ecnt, int E) {
    int e = blockIdx.x * 256 + threadIdx.x;
    if (e < E) atomicAdd(&ecnt[ei[E + e]], 1);  // dst = ei[1][e]
}

__global__ void k_dinv(const int* __restrict__ ecnt, float* __restrict__ dinv, int n) {
    int i = blockIdx.x * 256 + threadIdx.x;
    if (i < n) dinv[i] = rsqrtf((float)(ecnt[i] + 1));  // +1 self-loop
}

// ---------------- 3-phase device-wide exclusive scan ----------------
__global__ __launch_bounds__(1024) void k_scanA(const int* __restrict__ ecnt,
                                                int* __restrict__ rowptr,
                                                int* __restrict__ bsum, int n) {
    __shared__ int tmp[1024];
    int t = threadIdx.x;
    int gid = blockIdx.x * 1024 + t;
    int v = (gid < n) ? ecnt[gid] : 0;
    tmp[t] = v;
    __syncthreads();
    for (int off = 1; off < 1024; off <<= 1) {
        int u = (t >= off) ? tmp[t - off] : 0;
        __syncthreads();
        tmp[t] += u;
        __syncthreads();
    }
    if (gid < n) rowptr[gid] = tmp[t] - v;
    if (t == 1023) bsum[blockIdx.x] = tmp[1023];
}

__global__ void k_scanB(const int* __restrict__ bsum, int* __restrict__ boffs, int nb) {
    int t = threadIdx.x;
    int v = (t < nb) ? bsum[t] : 0;
    int inc = v;
#pragma unroll
    for (int off = 1; off < 64; off <<= 1) {
        int u = __shfl_up(inc, off);
        if (t >= off) inc += u;
    }
    if (t < nb) boffs[t] = inc - v;
    if (t == nb - 1) boffs[nb] = inc;
}

__global__ __launch_bounds__(1024) void k_scanC(int* __restrict__ rowptr,
                                                int* __restrict__ cur,
                                                const int* __restrict__ boffs,
                                                int n, int nb) {
    int gid = blockIdx.x * 1024 + threadIdx.x;
    if (gid < n) {
        int v = rowptr[gid] + boffs[blockIdx.x];
        rowptr[gid] = v;
        cur[gid] = v;
    } else if (gid == n) {
        rowptr[n] = boffs[nb];
    }
}

__global__ void k_fill(const int* __restrict__ ei, int* __restrict__ cur,
                       int* __restrict__ csr, int E) {
    int e = blockIdx.x * 256 + threadIdx.x;
    if (e < E) {
        int d = ei[E + e];
        int pos = atomicAdd(&cur[d], 1);
        csr[pos] = ei[e];  // src
    }
}

// ---------------- W1 -> bf16, transposed [128 cols][512 k] ----------------
__global__ void k_w1cvt(const float* __restrict__ W1, unsigned short* __restrict__ Btg) {
    int id = blockIdx.x * 256 + threadIdx.x;  // 65536 total
    int kk = id >> 7, c = id & 127;
    float v = (kk < F_IN) ? W1[kk * F_HID + c] : 0.f;
    Btg[c * 512 + kk] = pack_bf16(v);
}

// ---------------- GEMM1 (bf16 MFMA): hs16 = bf16((x @ W1) * dinv) ----------------
// BM=32 rows/block (grid 1563 -> ~6 blocks/CU), BK=64, 4 waves each 32x32 tile.
// Register prefetch of next chunk's A+B hides global latency under MFMA.
#define BM 32
#define BK 64
__global__ __launch_bounds__(256, 4) void k_gemm1_mfma(const float* __restrict__ x,
                                                       const unsigned short* __restrict__ Btg,
                                                       const float* __restrict__ dinv,
                                                       unsigned short* __restrict__ hs16, int n) {
    __shared__ unsigned short As[BM * BK];     // 4 KB, XOR-swizzled
    __shared__ unsigned short Bs[F_HID * BK];  // 16 KB, XOR-swizzled
    int t = threadIdx.x;
    int row0 = blockIdx.x * BM;
    int w = t >> 6, l = t & 63;

    // A staging coords: one 8-elem unit per thread
    int ar = t >> 3, acg = t & 7;
    int agrow = row0 + ar;
    int abyte = ar * 128 + ((acg * 16) ^ ((ar & 7) << 4));

    f32x4 acc[2][2] = {};

    float4 a0, a1;
    uint4 bq0, bq1, bq2, bq3;

#define LOAD_A(c, f0, f1)                                              \
    {                                                                  \
        int kbase = (c) * BK + acg * 8;                                \
        f0 = make_float4(0.f, 0.f, 0.f, 0.f);                          \
        f1 = make_float4(0.f, 0.f, 0.f, 0.f);                         \
        if (agrow < n) {                                               \
            const float* p = x + (long)agrow * F_IN + kbase;           \
            if (kbase + 4 <= F_IN) f0 = *(const float4*)p;             \
            if (kbase + 8 <= F_IN) f1 = *(const float4*)(p + 4);       \
        }                                                              \
    }
#define LOAD_B1(c, dst, uu)                                            \
    {                                                                  \
        int u = t + (uu) * 256;                                        \
        int r = u >> 3, cg = u & 7;                                    \
        dst = *(const uint4*)(Btg + r * 512 + (c) * BK + cg * 8);      \
    }

    LOAD_A(0, a0, a1);
    LOAD_B1(0, bq0, 0); LOAD_B1(0, bq1, 1); LOAD_B1(0, bq2, 2); LOAD_B1(0, bq3, 3);

    for (int c = 0; c < 8; ++c) {
        // ---- write staged regs to LDS
        uint4 pk;
        pk.x = pack_bf16x2(a0.x, a0.y);
        pk.y = pack_bf16x2(a0.z, a0.w);
        pk.z = pack_bf16x2(a1.x, a1.y);
        pk.w = pack_bf16x2(a1.z, a1.w);
        *(uint4*)((char*)As + abyte) = pk;
#pragma unroll
        for (int uu = 0; uu < 4; ++uu) {
            int u = t + uu * 256;
            int r = u >> 3, cg = u & 7;
            int byte = r * 128 + ((cg * 16) ^ ((r & 7) << 4));
            uint4 v = (uu == 0) ? bq0 : (uu == 1) ? bq1 : (uu == 2) ? bq2 : bq3;
            *(uint4*)((char*)Bs + byte) = v;
        }
        __syncthreads();

        // ---- issue next chunk's global loads (latency hides under ds_read+MFMA)
        float4 na0 = make_float4(0.f, 0.f, 0.f, 0.f), na1 = na0;
        uint4 nb0 = {}, nb1 = {}, nb2 = {}, nb3 = {};
        if (c < 7) {
            LOAD_A(c + 1, na0, na1);
            LOAD_B1(c + 1, nb0, 0); LOAD_B1(c + 1, nb1, 1);
            LOAD_B1(c + 1, nb2, 2); LOAD_B1(c + 1, nb3, 3);
        }

        // ---- fragments + MFMA
        int lr = l & 15;
        int lkb = (l >> 4) * 16;
        short8 af[2][2], bf[2][2];
#pragma unroll
        for (int mi = 0; mi < 2; ++mi)
#pragma unroll
            for (int ks = 0; ks < 2; ++ks) {
                int r = mi * 16 + lr;
                int byte = r * 128 + (((ks * 64) + lkb) ^ ((r & 7) << 4));
                af[mi][ks] = *(short8*)((char*)As + byte);
            }
#pragma unroll
        for (int ni = 0; ni < 2; ++ni)
#pragma unroll
            for (int ks = 0; ks < 2; ++ks) {
                int r = w * 32 + ni * 16 + lr;
                int byte = r * 128 + (((ks * 64) + lkb) ^ ((r & 7) << 4));
                bf[ni][ks] = *(short8*)((char*)Bs + byte);
            }
#pragma unroll
        for (int mi = 0; mi < 2; ++mi)
#pragma unroll
            for (int ni = 0; ni < 2; ++ni)
#pragma unroll
                for (int ks = 0; ks < 2; ++ks)
                    acc[mi][ni] = __builtin_amdgcn_mfma_f32_16x16x32_bf16(
                        af[mi][ks], bf[ni][ks], acc[mi][ni], 0, 0, 0);
        __syncthreads();

        a0 = na0; a1 = na1;
        bq0 = nb0; bq1 = nb1; bq2 = nb2; bq3 = nb3;
    }

    // ---- epilogue: col=lane&15, row=(lane>>4)*4+reg ; write bf16
#pragma unroll
    for (int mi = 0; mi < 2; ++mi) {
        int rb = row0 + mi * 16 + (l >> 4) * 4;
        float dv[4];
#pragma unroll
        for (int reg = 0; reg < 4; ++reg)
            dv[reg] = (rb + reg < n) ? dinv[rb + reg] : 0.f;
#pragma unroll
        for (int ni = 0; ni < 2; ++ni) {
            int col = w * 32 + ni * 16 + (l & 15);
#pragma unroll
            for (int reg = 0; reg < 4; ++reg) {
                int row = rb + reg;
                if (row < n) hs16[(long)row * F_HID + col] = pack_bf16(acc[mi][ni][reg] * dv[reg]);
            }
        }
    }
#undef LOAD_A
#undef LOAD_B1
}

// ---------------- gather layer 1: h1 = relu(dinv * (hs16[self]+sum hs16[src]) + b1) ----------------
__global__ __launch_bounds__(256) void k_gather1(const unsigned short* __restrict__ hs16,
                                                 const int* __restrict__ rowptr,
                                                 const int* __restrict__ csr,
                                                 const float* __restrict__ dinv,
                                                 const float* __restrict__ b1,
                                                 float* __restrict__ h1, int n) {
    int tid = blockIdx.x * 256 + threadIdx.x;
    int node = tid >> 5;
    if (node >= n) return;
    int q = tid & 31;
    float4 v = make_float4(0.f, 0.f, 0.f, 0.f);
    {
        uint2 u = *(const uint2*)(hs16 + (long)node * F_HID + q * 4);  // self
        v.x = __uint_as_float(u.x << 16);
        v.y = __uint_as_float(u.x & 0xFFFF0000u);
        v.z = __uint_as_float(u.y << 16);
        v.w = __uint_as_float(u.y & 0xFFFF0000u);
    }
    int lo = rowptr[node], hi = rowptr[node + 1];
    for (int e = lo; e < hi; ++e) {
        int s = csr[e];
        uint2 u = *(const uint2*)(hs16 + (long)s * F_HID + q * 4);
        v.x += __uint_as_float(u.x << 16);
        v.y += __uint_as_float(u.x & 0xFFFF0000u);
        v.z += __uint_as_float(u.y << 16);
        v.w += __uint_as_float(u.y & 0xFFFF0000u);
    }
    float dv = dinv[node];
    float4 bb = *(const float4*)&b1[q * 4];
    *(float4*)&h1[(long)node * F_HID + q * 4] =
        make_float4(fmaxf(dv * v.x + bb.x, 0.f), fmaxf(dv * v.y + bb.y, 0.f),
                    fmaxf(dv * v.z + bb.z, 0.f), fmaxf(dv * v.w + bb.w, 0.f));
}

// ---------------- GEMM2: hs2_16 = bf16((h1 @ W2) * dinv), padded to 64 cols ----------------
__global__ __launch_bounds__(256) void k_gemm2(const float* __restrict__ h1,
                                               const float* __restrict__ W2,
                                               const float* __restrict__ dinv,
                                               unsigned short* __restrict__ hs2, int n) {
    __shared__ float w2s[F_HID * F_OUT];
    __shared__ float rs[4][F_HID];
    for (int i = threadIdx.x; i < F_HID * F_OUT; i += 256) w2s[i] = W2[i];
    int w = threadIdx.x >> 6, lane = threadIdx.x & 63;
    int node = blockIdx.x * 4 + w;
    if (node < n) {
        for (int k = lane; k < F_HID; k += 64)
            rs[w][k] = h1[(long)node * F_HID + k];
    }
    __syncthreads();
    if (node < n) {
        float v = 0.f;
        if (lane < F_OUT) {
            float s = 0.f;
#pragma unroll 8
            for (int k = 0; k < F_HID; ++k) s += rs[w][k] * w2s[k * F_OUT + lane];
            v = s * dinv[node];
        }
        hs2[(long)node * 64 + lane] = pack_bf16(v);  // pad cols 47..63 = 0
    }
}

// ---------------- gather layer 2 + bias + log_softmax ----------------
__global__ __launch_bounds__(256) void k_out(const unsigned short* __restrict__ hs2,
                                             const int* __restrict__ rowptr,
                                             const int* __restrict__ csr,
                                             const float* __restrict__ dinv,
                                             const float* __restrict__ b2,
                                             float* __restrict__ out, int n) {
    int tid = blockIdx.x * 256 + threadIdx.x;
    int node = tid >> 5;
    if (node >= n) return;
    int q = tid & 31;
    int c0 = 2 * q, c1 = 2 * q + 1;
    float v0, v1;
    {
        unsigned u = *(const unsigned*)(hs2 + (long)node * 64 + c0);  // self
        v0 = __uint_as_float(u << 16);
        v1 = __uint_as_float(u & 0xFFFF0000u);
    }
    int lo = rowptr[node], hi = rowptr[node + 1];
    for (int e = lo; e < hi; ++e) {
        int s = csr[e];
        unsigned u = *(const unsigned*)(hs2 + (long)s * 64 + c0);
        v0 += __uint_as_float(u << 16);
        v1 += __uint_as_float(u & 0xFFFF0000u);
    }
    float dv = dinv[node];
    float z0 = (c0 < F_OUT) ? v0 * dv + b2[c0] : -INFINITY;
    float z1 = (c1 < F_OUT) ? v1 * dv + b2[c1] : -INFINITY;
    float m = fmaxf(z0, z1);
#pragma unroll
    for (int o = 16; o; o >>= 1) m = fmaxf(m, __shfl_xor(m, o));
    float sum = ((c0 < F_OUT) ? __expf(z0 - m) : 0.f) + ((c1 < F_OUT) ? __expf(z1 - m) : 0.f);
#pragma unroll
    for (int o = 16; o; o >>= 1) sum += __shfl_xor(sum, o);
    float ls = logf(sum) + m;
    if (c0 < F_OUT) out[(long)node * F_OUT + c0] = z0 - ls;
    if (c1 < F_OUT) out[(long)node * F_OUT + c1] = z1 - ls;
}

extern "C" void kernel_launch(void* const* d_in, const int* in_sizes, int n_in,
                              void* d_out, int out_size, void* d_ws, size_t ws_size,
                              hipStream_t stream) {
    const float* x  = (const float*)d_in[0];
    const float* W1 = (const float*)d_in[1];
    const float* b1 = (const float*)d_in[2];
    const float* W2 = (const float*)d_in[3];
    const float* b2 = (const float*)d_in[4];
    const int*   ei = (const int*)d_in[5];

    int n = in_sizes[0] / F_IN;      // 50000
    int E = in_sizes[5] / 2;         // 800000
    float* out = (float*)d_out;

    // workspace layout
    char* ws = (char*)d_ws;
    float* dinv   = (float*)(ws + 0);          // 200 KB
    int*   ecnt   = (int*)  (ws + 200704);
    int*   rowptr = (int*)  (ws + 401408);     // n+1 ints
    int*   cur    = (int*)  (ws + 602112);     // dead after k_fill; Btg aliases it
    unsigned short* Btg = (unsigned short*)(ws + 602112);  // 128 KB (ends 733184)
    int*   bsum   = (int*)  (ws + 733184);
    int*   boffs  = (int*)  (ws + 737280);
    int*   csr    = (int*)  (ws + 802816);     // 3.2 MB
    unsigned short* hs16  = (unsigned short*)(ws + 4003840);   // 12.8 MB
    unsigned short* hs2   = (unsigned short*)(ws + 16804864);  // 6.4 MB
    float* h1     = (float*)(ws + 29603840);   // 25.6 MB

    int nb = (n + 255) / 256;
    int eb = (E + 255) / 256;
    int sb = (n + 1023) / 1024;
    k_zero<<<nb, 256, 0, stream>>>(ecnt, n);
    k_deg_count<<<eb, 256, 0, stream>>>(ei, ecnt, E);
    k_dinv<<<nb, 256, 0, stream>>>(ecnt, dinv, n);
    k_scanA<<<sb, 1024, 0, stream>>>(ecnt, rowptr, bsum, n);
    k_scanB<<<1, 64, 0, stream>>>(bsum, boffs, sb);
    k_scanC<<<sb, 1024, 0, stream>>>(rowptr, cur, boffs, n, sb);
    k_fill<<<eb, 256, 0, stream>>>(ei, cur, csr, E);
    k_w1cvt<<<256, 256, 0, stream>>>(W1, Btg);

    k_gemm1_mfma<<<(n + BM - 1) / BM, 256, 0, stream>>>(x, Btg, dinv, hs16, n);
    k_gather1<<<(n * 32 + 255) / 256, 256, 0, stream>>>(hs16, rowptr, csr, dinv, b1, h1, n);
    k_gemm2<<<(n + 3) / 4, 256, 0, stream>>>(h1, W2, dinv, hs2, n);
    k_out<<<(n * 32 + 255) / 256, 256, 0, stream>>>(hs2, rowptr, csr, dinv, b2, out, n);
}

// Round 7
// 271.184 us; speedup vs baseline: 6.7136x; 1.0682x over previous
//
#include <hip/hip_runtime.h>
#include <math.h>

#define F_IN 500
#define F_HID 128
#define F_OUT 47
#define NGRP 8

typedef __attribute__((ext_vector_type(8))) short short8;
typedef __attribute__((ext_vector_type(4))) float f32x4;

__device__ inline unsigned pack_bf16x2(float a, float b) {
    unsigned ua = __float_as_uint(a), ub = __float_as_uint(b);
    ua = (ua + 0x7FFFu + ((ua >> 16) & 1u)) >> 16;
    ub = (ub + 0x7FFFu + ((ub >> 16) & 1u)) >> 16;
    return ua | (ub << 16);
}
__device__ inline unsigned short pack_bf16(float a) {
    unsigned u = __float_as_uint(a);
    return (unsigned short)((u + 0x7FFFu + ((u >> 16) & 1u)) >> 16);
}

// ---------------- degree / norm / CSR build ----------------
__global__ void k_zero(int* __restrict__ p, int n) {
    int i = blockIdx.x * 256 + threadIdx.x;
    if (i < n) p[i] = 0;
}

// XCD-partitioned: group g = blockIdx&7 handles dst in [g*n/8,(g+1)*n/8)
// -> each ecnt line is only dirtied by one block-group (one L2), killing
//    cross-XCD false-sharing writebacks.
__global__ void k_deg_count(const int* __restrict__ ei, int* __restrict__ ecnt,
                            int E, int n) {
    int g = blockIdx.x & (NGRP - 1);
    int bi = blockIdx.x >> 3;
    int nbg = gridDim.x >> 3;
    int lo = (int)((long)g * n / NGRP), hi = (int)((long)(g + 1) * n / NGRP);
    for (int e = bi * 256 + threadIdx.x; e < E; e += nbg * 256) {
        int d = ei[E + e];
        if (d >= lo && d < hi) atomicAdd(&ecnt[d], 1);
    }
}

__global__ void k_dinv(const int* __restrict__ ecnt, float* __restrict__ dinv, int n) {
    int i = blockIdx.x * 256 + threadIdx.x;
    if (i < n) dinv[i] = rsqrtf((float)(ecnt[i] + 1));  // +1 self-loop
}

// ---------------- 3-phase device-wide exclusive scan ----------------
__global__ __launch_bounds__(1024) void k_scanA(const int* __restrict__ ecnt,
                                                int* __restrict__ rowptr,
                                                int* __restrict__ bsum, int n) {
    __shared__ int tmp[1024];
    int t = threadIdx.x;
    int gid = blockIdx.x * 1024 + t;
    int v = (gid < n) ? ecnt[gid] : 0;
    tmp[t] = v;
    __syncthreads();
    for (int off = 1; off < 1024; off <<= 1) {
        int u = (t >= off) ? tmp[t - off] : 0;
        __syncthreads();
        tmp[t] += u;
        __syncthreads();
    }
    if (gid < n) rowptr[gid] = tmp[t] - v;
    if (t == 1023) bsum[blockIdx.x] = tmp[1023];
}

__global__ void k_scanB(const int* __restrict__ bsum, int* __restrict__ boffs, int nb) {
    int t = threadIdx.x;
    int v = (t < nb) ? bsum[t] : 0;
    int inc = v;
#pragma unroll
    for (int off = 1; off < 64; off <<= 1) {
        int u = __shfl_up(inc, off);
        if (t >= off) inc += u;
    }
    if (t < nb) boffs[t] = inc - v;
    if (t == nb - 1) boffs[nb] = inc;
}

__global__ __launch_bounds__(1024) void k_scanC(int* __restrict__ rowptr,
                                                int* __restrict__ cur,
                                                const int* __restrict__ boffs,
                                                int n, int nb) {
    int gid = blockIdx.x * 1024 + threadIdx.x;
    if (gid < n) {
        int v = rowptr[gid] + boffs[blockIdx.x];
        rowptr[gid] = v;
        cur[gid] = v;
    } else if (gid == n) {
        rowptr[n] = boffs[nb];
    }
}

// XCD-partitioned CSR fill (same grouping as k_deg_count): group g's csr
// region is a contiguous slice written only by that group's blocks.
__global__ void k_fill(const int* __restrict__ ei, int* __restrict__ cur,
                       int* __restrict__ csr, int E, int n) {
    int g = blockIdx.x & (NGRP - 1);
    int bi = blockIdx.x >> 3;
    int nbg = gridDim.x >> 3;
    int lo = (int)((long)g * n / NGRP), hi = (int)((long)(g + 1) * n / NGRP);
    for (int e = bi * 256 + threadIdx.x; e < E; e += nbg * 256) {
        int d = ei[E + e];
        if (d >= lo && d < hi) {
            int pos = atomicAdd(&cur[d], 1);
            csr[pos] = ei[e];  // src
        }
    }
}

// ---------------- W1 -> bf16, transposed [128 cols][512 k] ----------------
__global__ void k_w1cvt(const float* __restrict__ W1, unsigned short* __restrict__ Btg) {
    int id = blockIdx.x * 256 + threadIdx.x;  // 65536 total
    int kk = id >> 7, c = id & 127;
    float v = (kk < F_IN) ? W1[kk * F_HID + c] : 0.f;
    Btg[c * 512 + kk] = pack_bf16(v);
}

// ---------------- GEMM1 (bf16 MFMA): hs16 = bf16((x @ W1) * dinv) ----------------
#define BM 32
#define BK 64
__global__ __launch_bounds__(256, 4) void k_gemm1_mfma(const float* __restrict__ x,
                                                       const unsigned short* __restrict__ Btg,
                                                       const float* __restrict__ dinv,
                                                       unsigned short* __restrict__ hs16, int n) {
    __shared__ unsigned short As[BM * BK];     // 4 KB, XOR-swizzled
    __shared__ unsigned short Bs[F_HID * BK];  // 16 KB, XOR-swizzled
    int t = threadIdx.x;
    int row0 = blockIdx.x * BM;
    int w = t >> 6, l = t & 63;

    int ar = t >> 3, acg = t & 7;
    int agrow = row0 + ar;
    int abyte = ar * 128 + ((acg * 16) ^ ((ar & 7) << 4));

    f32x4 acc[2][2] = {};

    float4 a0, a1;
    uint4 bq0, bq1, bq2, bq3;

#define LOAD_A(c, f0, f1)                                              \
    {                                                                  \
        int kbase = (c) * BK + acg * 8;                                \
        f0 = make_float4(0.f, 0.f, 0.f, 0.f);                          \
        f1 = make_float4(0.f, 0.f, 0.f, 0.f);                         \
        if (agrow < n) {                                               \
            const float* p = x + (long)agrow * F_IN + kbase;           \
            if (kbase + 4 <= F_IN) f0 = *(const float4*)p;             \
            if (kbase + 8 <= F_IN) f1 = *(const float4*)(p + 4);       \
        }                                                              \
    }
#define LOAD_B1(c, dst, uu)                                            \
    {                                                                  \
        int u = t + (uu) * 256;                                        \
        int r = u >> 3, cg = u & 7;                                    \
        dst = *(const uint4*)(Btg + r * 512 + (c) * BK + cg * 8);      \
    }

    LOAD_A(0, a0, a1);
    LOAD_B1(0, bq0, 0); LOAD_B1(0, bq1, 1); LOAD_B1(0, bq2, 2); LOAD_B1(0, bq3, 3);

    for (int c = 0; c < 8; ++c) {
        uint4 pk;
        pk.x = pack_bf16x2(a0.x, a0.y);
        pk.y = pack_bf16x2(a0.z, a0.w);
        pk.z = pack_bf16x2(a1.x, a1.y);
        pk.w = pack_bf16x2(a1.z, a1.w);
        *(uint4*)((char*)As + abyte) = pk;
#pragma unroll
        for (int uu = 0; uu < 4; ++uu) {
            int u = t + uu * 256;
            int r = u >> 3, cg = u & 7;
            int byte = r * 128 + ((cg * 16) ^ ((r & 7) << 4));
            uint4 v = (uu == 0) ? bq0 : (uu == 1) ? bq1 : (uu == 2) ? bq2 : bq3;
            *(uint4*)((char*)Bs + byte) = v;
        }
        __syncthreads();

        float4 na0 = make_float4(0.f, 0.f, 0.f, 0.f), na1 = na0;
        uint4 nb0 = {}, nb1 = {}, nb2 = {}, nb3 = {};
        if (c < 7) {
            LOAD_A(c + 1, na0, na1);
            LOAD_B1(c + 1, nb0, 0); LOAD_B1(c + 1, nb1, 1);
            LOAD_B1(c + 1, nb2, 2); LOAD_B1(c + 1, nb3, 3);
        }

        int lr = l & 15;
        int lkb = (l >> 4) * 16;
        short8 af[2][2], bf[2][2];
#pragma unroll
        for (int mi = 0; mi < 2; ++mi)
#pragma unroll
            for (int ks = 0; ks < 2; ++ks) {
                int r = mi * 16 + lr;
                int byte = r * 128 + (((ks * 64) + lkb) ^ ((r & 7) << 4));
                af[mi][ks] = *(short8*)((char*)As + byte);
            }
#pragma unroll
        for (int ni = 0; ni < 2; ++ni)
#pragma unroll
            for (int ks = 0; ks < 2; ++ks) {
                int r = w * 32 + ni * 16 + lr;
                int byte = r * 128 + (((ks * 64) + lkb) ^ ((r & 7) << 4));
                bf[ni][ks] = *(short8*)((char*)Bs + byte);
            }
#pragma unroll
        for (int mi = 0; mi < 2; ++mi)
#pragma unroll
            for (int ni = 0; ni < 2; ++ni)
#pragma unroll
                for (int ks = 0; ks < 2; ++ks)
                    acc[mi][ni] = __builtin_amdgcn_mfma_f32_16x16x32_bf16(
                        af[mi][ks], bf[ni][ks], acc[mi][ni], 0, 0, 0);
        __syncthreads();

        a0 = na0; a1 = na1;
        bq0 = nb0; bq1 = nb1; bq2 = nb2; bq3 = nb3;
    }

#pragma unroll
    for (int mi = 0; mi < 2; ++mi) {
        int rb = row0 + mi * 16 + (l >> 4) * 4;
        float dv[4];
#pragma unroll
        for (int reg = 0; reg < 4; ++reg)
            dv[reg] = (rb + reg < n) ? dinv[rb + reg] : 0.f;
#pragma unroll
        for (int ni = 0; ni < 2; ++ni) {
            int col = w * 32 + ni * 16 + (l & 15);
#pragma unroll
            for (int reg = 0; reg < 4; ++reg) {
                int row = rb + reg;
                if (row < n) hs16[(long)row * F_HID + col] = pack_bf16(acc[mi][ni][reg] * dv[reg]);
            }
        }
    }
#undef LOAD_A
#undef LOAD_B1
}

// ---------------- gather layer 1: h1 = relu(dinv * (hs16[self]+sum hs16[src]) + b1) ----------------
__global__ __launch_bounds__(256) void k_gather1(const unsigned short* __restrict__ hs16,
                                                 const int* __restrict__ rowptr,
                                                 const int* __restrict__ csr,
                                                 const float* __restrict__ dinv,
                                                 const float* __restrict__ b1,
                                                 float* __restrict__ h1, int n) {
    int tid = blockIdx.x * 256 + threadIdx.x;
    int node = tid >> 5;
    if (node >= n) return;
    int q = tid & 31;
    float4 v = make_float4(0.f, 0.f, 0.f, 0.f);
    {
        uint2 u = *(const uint2*)(hs16 + (long)node * F_HID + q * 4);  // self
        v.x = __uint_as_float(u.x << 16);
        v.y = __uint_as_float(u.x & 0xFFFF0000u);
        v.z = __uint_as_float(u.y << 16);
        v.w = __uint_as_float(u.y & 0xFFFF0000u);
    }
    int lo = rowptr[node], hi = rowptr[node + 1];
    for (int e = lo; e < hi; ++e) {
        int s = csr[e];
        uint2 u = *(const uint2*)(hs16 + (long)s * F_HID + q * 4);
        v.x += __uint_as_float(u.x << 16);
        v.y += __uint_as_float(u.x & 0xFFFF0000u);
        v.z += __uint_as_float(u.y << 16);
        v.w += __uint_as_float(u.y & 0xFFFF0000u);
    }
    float dv = dinv[node];
    float4 bb = *(const float4*)&b1[q * 4];
    *(float4*)&h1[(long)node * F_HID + q * 4] =
        make_float4(fmaxf(dv * v.x + bb.x, 0.f), fmaxf(dv * v.y + bb.y, 0.f),
                    fmaxf(dv * v.z + bb.z, 0.f), fmaxf(dv * v.w + bb.w, 0.f));
}

// ---------------- GEMM2: hs2_16 = bf16((h1 @ W2) * dinv), padded to 64 cols ----------------
__global__ __launch_bounds__(256) void k_gemm2(const float* __restrict__ h1,
                                               const float* __restrict__ W2,
                                               const float* __restrict__ dinv,
                                               unsigned short* __restrict__ hs2, int n) {
    __shared__ float w2s[F_HID * F_OUT];
    __shared__ float rs[4][F_HID];
    for (int i = threadIdx.x; i < F_HID * F_OUT; i += 256) w2s[i] = W2[i];
    int w = threadIdx.x >> 6, lane = threadIdx.x & 63;
    int node = blockIdx.x * 4 + w;
    if (node < n) {
        for (int k = lane; k < F_HID; k += 64)
            rs[w][k] = h1[(long)node * F_HID + k];
    }
    __syncthreads();
    if (node < n) {
        float v = 0.f;
        if (lane < F_OUT) {
            float s = 0.f;
#pragma unroll 8
            for (int k = 0; k < F_HID; ++k) s += rs[w][k] * w2s[k * F_OUT + lane];
            v = s * dinv[node];
        }
        hs2[(long)node * 64 + lane] = pack_bf16(v);  // pad cols 47..63 = 0
    }
}

// ---------------- gather layer 2 + bias + log_softmax ----------------
__global__ __launch_bounds__(256) void k_out(const unsigned short* __restrict__ hs2,
                                             const int* __restrict__ rowptr,
                                             const int* __restrict__ csr,
                                             const float* __restrict__ dinv,
                                             const float* __restrict__ b2,
                                             float* __restrict__ out, int n) {
    int tid = blockIdx.x * 256 + threadIdx.x;
    int node = tid >> 5;
    if (node >= n) return;
    int q = tid & 31;
    int c0 = 2 * q, c1 = 2 * q + 1;
    float v0, v1;
    {
        unsigned u = *(const unsigned*)(hs2 + (long)node * 64 + c0);  // self
        v0 = __uint_as_float(u << 16);
        v1 = __uint_as_float(u & 0xFFFF0000u);
    }
    int lo = rowptr[node], hi = rowptr[node + 1];
    for (int e = lo; e < hi; ++e) {
        int s = csr[e];
        unsigned u = *(const unsigned*)(hs2 + (long)s * 64 + c0);
        v0 += __uint_as_float(u << 16);
        v1 += __uint_as_float(u & 0xFFFF0000u);
    }
    float dv = dinv[node];
    float z0 = (c0 < F_OUT) ? v0 * dv + b2[c0] : -INFINITY;
    float z1 = (c1 < F_OUT) ? v1 * dv + b2[c1] : -INFINITY;
    float m = fmaxf(z0, z1);
#pragma unroll
    for (int o = 16; o; o >>= 1) m = fmaxf(m, __shfl_xor(m, o));
    float sum = ((c0 < F_OUT) ? __expf(z0 - m) : 0.f) + ((c1 < F_OUT) ? __expf(z1 - m) : 0.f);
#pragma unroll
    for (int o = 16; o; o >>= 1) sum += __shfl_xor(sum, o);
    float ls = logf(sum) + m;
    if (c0 < F_OUT) out[(long)node * F_OUT + c0] = z0 - ls;
    if (c1 < F_OUT) out[(long)node * F_OUT + c1] = z1 - ls;
}

extern "C" void kernel_launch(void* const* d_in, const int* in_sizes, int n_in,
                              void* d_out, int out_size, void* d_ws, size_t ws_size,
                              hipStream_t stream) {
    const float* x  = (const float*)d_in[0];
    const float* W1 = (const float*)d_in[1];
    const float* b1 = (const float*)d_in[2];
    const float* W2 = (const float*)d_in[3];
    const float* b2 = (const float*)d_in[4];
    const int*   ei = (const int*)d_in[5];

    int n = in_sizes[0] / F_IN;      // 50000
    int E = in_sizes[5] / 2;         // 800000
    float* out = (float*)d_out;

    // workspace layout
    char* ws = (char*)d_ws;
    float* dinv   = (float*)(ws + 0);          // 200 KB
    int*   ecnt   = (int*)  (ws + 200704);
    int*   rowptr = (int*)  (ws + 401408);     // n+1 ints
    int*   cur    = (int*)  (ws + 602112);     // dead after k_fill; Btg aliases it
    unsigned short* Btg = (unsigned short*)(ws + 602112);  // 128 KB (ends 733184)
    int*   bsum   = (int*)  (ws + 733184);
    int*   boffs  = (int*)  (ws + 737280);
    int*   csr    = (int*)  (ws + 802816);     // 3.2 MB
    unsigned short* hs16  = (unsigned short*)(ws + 4003840);   // 12.8 MB
    unsigned short* hs2   = (unsigned short*)(ws + 16804864);  // 6.4 MB
    float* h1     = (float*)(ws + 29603840);   // 25.6 MB

    int nb = (n + 255) / 256;
    int sb = (n + 1023) / 1024;
    k_zero<<<nb, 256, 0, stream>>>(ecnt, n);
    k_deg_count<<<1024, 256, 0, stream>>>(ei, ecnt, E, n);
    k_dinv<<<nb, 256, 0, stream>>>(ecnt, dinv, n);
    k_scanA<<<sb, 1024, 0, stream>>>(ecnt, rowptr, bsum, n);
    k_scanB<<<1, 64, 0, stream>>>(bsum, boffs, sb);
    k_scanC<<<sb, 1024, 0, stream>>>(rowptr, cur, boffs, n, sb);
    k_fill<<<1024, 256, 0, stream>>>(ei, cur, csr, E, n);
    k_w1cvt<<<256, 256, 0, stream>>>(W1, Btg);

    k_gemm1_mfma<<<(n + BM - 1) / BM, 256, 0, stream>>>(x, Btg, dinv, hs16, n);
    k_gather1<<<(n * 32 + 255) / 256, 256, 0, stream>>>(hs16, rowptr, csr, dinv, b1, h1, n);
    k_gemm2<<<(n + 3) / 4, 256, 0, stream>>>(h1, W2, dinv, hs2, n);
    k_out<<<(n * 32 + 255) / 256, 256, 0, stream>>>(hs2, rowptr, csr, dinv, b2, out, n);
}